// Round 13
// baseline (372.236 us; speedup 1.0000x reference)
//
#include <hip/hip_runtime.h>

typedef __attribute__((ext_vector_type(8))) short bf16x8;
typedef __attribute__((ext_vector_type(4))) float f32x4;
typedef __attribute__((ext_vector_type(16))) float f32x16;
typedef __attribute__((ext_vector_type(4))) int int4v;
typedef __attribute__((ext_vector_type(4))) unsigned short us4;

#define LOG2E 1.4426950408889634f

__device__ __forceinline__ unsigned short f2b(float f){
  unsigned u = __builtin_bit_cast(unsigned, f);
  u = (u + 0x7fffu + ((u >> 16) & 1u)) >> 16;
  return (unsigned short)u;
}
// round-to-nearest (ties up) — 0.5 ulp, 2 VALU ops
__device__ __forceinline__ unsigned short f2bf(float f){
  unsigned u = __builtin_bit_cast(unsigned, f);
  return (unsigned short)((u + 0x8000u) >> 16);
}

__device__ __forceinline__ f32x4 mfma16(bf16x8 a, bf16x8 b, f32x4 c){
  return __builtin_amdgcn_mfma_f32_16x16x32_bf16(a, b, c, 0, 0, 0);
}
__device__ __forceinline__ f32x16 mfma32(bf16x8 a, bf16x8 b, f32x16 c){
  return __builtin_amdgcn_mfma_f32_32x32x16_bf16(a, b, c, 0, 0, 0);
}
// 3-input max — clang fuses nested fmaxf to v_max3_f32 (T17)
__device__ __forceinline__ float max3f(float a, float b, float c){
  return fmaxf(fmaxf(a, b), c);
}

typedef const __attribute__((address_space(1))) void* gas_t;
typedef __attribute__((address_space(3))) void* las_t;
__device__ __forceinline__ void glds16(const void* g, void* l){
  __builtin_amdgcn_global_load_lds((gas_t)g, (las_t)l, 16, 0, 0);
}

// ---------------- cast fp32 -> bf16 (vectorized) ----------------
__global__ __launch_bounds__(256) void cast_bf16_kernel(const float4* __restrict__ in,
                                                        us4* __restrict__ out, int n4){
  int i = blockIdx.x * 256 + threadIdx.x;
  int stride = gridDim.x * 256;
  for (; i < n4; i += stride){
    float4 v = in[i];
    us4 o; o.x = f2b(v.x); o.y = f2b(v.y); o.z = f2b(v.z); o.w = f2b(v.w);
    out[i] = o;
  }
}

// ------ merged transpose+cast for both weights: in[R][C] fp32 -> out[C][R] bf16 ----
__global__ __launch_bounds__(256) void transpose2_kernel(const float* __restrict__ in0,
                                                         unsigned short* __restrict__ out0,
                                                         const float* __restrict__ in1,
                                                         unsigned short* __restrict__ out1){
  __shared__ float tile[64][65];
  const int tid = threadIdx.x;
  const bool first = blockIdx.x < 96;
  const float* in = first ? in0 : in1;
  unsigned short* out = first ? out0 : out1;
  const int C = first ? 6144 : 2048;
  const int R = 2048;
  const int bx = first ? blockIdx.x : blockIdx.x - 96;
  const int c0 = bx * 64, r0 = blockIdx.y * 64;
#pragma unroll
  for (int p = 0; p < 4; p++){
    int idx = p * 1024 + tid * 4;
    int rr = idx >> 6, cc = idx & 63;
    float4 v = *(const float4*)(in + (size_t)(r0 + rr) * C + (c0 + cc));
    tile[rr][cc+0] = v.x; tile[rr][cc+1] = v.y; tile[rr][cc+2] = v.z; tile[rr][cc+3] = v.w;
  }
  __syncthreads();
#pragma unroll
  for (int p = 0; p < 4; p++){
    int idx = p * 1024 + tid * 4;
    int crow = idx >> 6, rcol = idx & 63;
    us4 o;
    o.x = f2b(tile[rcol+0][crow]); o.y = f2b(tile[rcol+1][crow]);
    o.z = f2b(tile[rcol+2][crow]); o.w = f2b(tile[rcol+3][crow]);
    *(us4*)(out + (size_t)(c0 + crow) * R + (r0 + rcol)) = o;
  }
}

// ------- bf16 GEMM (R10: 128^2 tile, 512-thr wave split): C = A*BT^T + bias -------
// BK=64, 2 LDS buffers (64 KB -> 2 blk/CU => 16 waves/CU), glds16 staging w/
// pre-swizzled global source (rule #21), single __syncthreads per K-step.
// 8 waves 2x4: wave owns 64x32 output (4 mf x 2 nf), 16 MFMA/step.
template<int MODE>
__global__ __launch_bounds__(512, 4) void gemm_kernel(
    const unsigned short* __restrict__ A,
    const unsigned short* __restrict__ BT,
    const float* __restrict__ bias,
    unsigned short* __restrict__ qb,
    unsigned short* __restrict__ kb,
    unsigned short* __restrict__ vtb,
    float* __restrict__ outp)
{
  constexpr int K = 2048;
  constexpr int NT = K / 64;
  __shared__ short lA[2][128 * 64];
  __shared__ short lB[2][128 * 64];
  const int tid = threadIdx.x, lane = tid & 63, wid = tid >> 6;
  const int l16 = lane & 15, lhi = lane >> 4;
  const int wm = wid >> 2, wn = wid & 3;
  const int bm = blockIdx.x, bn = blockIdx.y;

  const char* Abase = (const char*)(A + (size_t)bm * 128 * K);
  const char* Bbase = (const char*)(BT + (size_t)bn * 128 * K);

  // staging: chunk c = wid*2 + j (1 KB each, 16 chunks per operand)
  const char* agp[2]; const char* bgp[2];
  int dst[2];
#pragma unroll
  for (int j = 0; j < 2; j++){
    int c = wid * 2 + j;
    int row = c * 8 + (lane >> 3);
    int col = ((lane & 7) * 16) ^ ((lane >> 3) << 4);   // row&7 == lane>>3
    agp[j] = Abase + (size_t)row * (K * 2) + col;       // + kt*128
    bgp[j] = Bbase + (size_t)row * (K * 2) + col;
    dst[j] = c * 1024;                   // HW adds lane*16
  }

  auto stage = [&](int kt, int buf){
    char* bA = (char*)lA[buf]; char* bB = (char*)lB[buf];
#pragma unroll
    for (int j = 0; j < 2; j++){
      glds16(agp[j] + kt * 128, bA + dst[j]);
      glds16(bgp[j] + kt * 128, bB + dst[j]);
    }
  };

  f32x4 acc[4][2];
  f32x4 z = {0.f, 0.f, 0.f, 0.f};
#pragma unroll
  for (int i = 0; i < 4; i++)
#pragma unroll
    for (int j = 0; j < 2; j++) acc[i][j] = z;

  stage(0, 0);
  __syncthreads();
  int cur = 0;
  for (int kt = 0; kt < NT; ++kt){
    if (kt + 1 < NT) stage(kt + 1, cur ^ 1);   // prefetch into cur^1
#pragma unroll
    for (int kk = 0; kk < 2; kk++){
      bf16x8 af[4], bfr[2];
#pragma unroll
      for (int mf = 0; mf < 4; mf++){
        int row = wm * 64 + mf * 16 + l16;
        int byte = (row * 128 + kk * 64 + lhi * 16) ^ ((row & 7) << 4);
        af[mf] = *(const bf16x8*)((const char*)lA[cur] + byte);
      }
#pragma unroll
      for (int nf = 0; nf < 2; nf++){
        int row = wn * 32 + nf * 16 + l16;
        int byte = (row * 128 + kk * 64 + lhi * 16) ^ ((row & 7) << 4);
        bfr[nf] = *(const bf16x8*)((const char*)lB[cur] + byte);
      }
      __builtin_amdgcn_s_setprio(1);
#pragma unroll
      for (int mf = 0; mf < 4; mf++)
#pragma unroll
        for (int nf = 0; nf < 2; nf++)
          acc[mf][nf] = mfma16(af[mf], bfr[nf], acc[mf][nf]);
      __builtin_amdgcn_s_setprio(0);
    }
    __syncthreads();   // drains vmcnt (glds of cur^1 complete) + retires reads of cur
    cur ^= 1;
  }

  const int row0 = bm * 128 + wm * 64;
  const int col0 = bn * 128 + wn * 32;
  if (MODE == 0){
#pragma unroll
    for (int nf = 0; nf < 2; nf++){
      int colb = col0 + nf * 16;
      float bv = bias[colb + l16];
      int which = colb >> 11;
      int h = (colb >> 7) & 15;
      int e = (colb & 127) + l16;
#pragma unroll
      for (int mf = 0; mf < 4; mf++){
#pragma unroll
        for (int r = 0; r < 4; r++){
          int row = row0 + mf * 16 + lhi * 4 + r;
          int b = row >> 11, t = row & 2047;
          float v = acc[mf][nf][r] + bv;
          size_t bh = (size_t)(b * 16 + h);
          if (which == 0)      qb[(bh * 2048 + t) * 128 + e] = f2b(v * 0.08838834764831845f);
          else if (which == 1) kb[(bh * 2048 + t) * 128 + e] = f2b(v);
          else                 vtb[(bh * 128 + e) * 2048 + t] = f2b(v);
        }
      }
    }
  } else {
#pragma unroll
    for (int nf = 0; nf < 2; nf++){
      int col = col0 + nf * 16 + l16;
      float bv = bias[col];
#pragma unroll
      for (int mf = 0; mf < 4; mf++){
#pragma unroll
        for (int r = 0; r < 4; r++){
          int row = row0 + mf * 16 + lhi * 4 + r;
          outp[(size_t)row * 2048 + col] = acc[mf][nf][r] + bv;
        }
      }
    }
  }
}

// ------- flash attention v3: 32x32 MFMA, swapped QK^T, in-reg softmax,
//         V read DIRECT from global/L2 (no LDS round-trip; Common-mistake #7),
//         K LDS dbuf only (32 KB) -> 3 blocks/CU (launch_bounds(256,3)) ----------
__global__ __launch_bounds__(256, 3) void attn_kernel(
    const unsigned short* __restrict__ q_buf,
    const unsigned short* __restrict__ k_buf,
    const unsigned short* __restrict__ vt_buf,
    unsigned short* __restrict__ attn_out)
{
  constexpr int L = 2048, NT = L / 64;
  __shared__ short lK[2][64 * 128];   // [key][e] rows 256 B, swizzled ^((key&7)<<4)
  const int tid = threadIdx.x, lane = tid & 63, wid = tid >> 6;
  const int l31 = lane & 31, lhi2 = lane >> 5;

  // XCD-locality remap: 4 heads per XCD -> K+V working set ~4 MB = L2 size.
  const int d = blockIdx.y * 16 + blockIdx.x;
  const int bh = (d & 7) + 8 * ((d >> 3) & 3);
  const int qi = d >> 5;
  const int qbase = qi * 128;

  const unsigned short* qp = q_buf + (size_t)bh * L * 128;
  const char* kp2 = (const char*)(k_buf + (size_t)bh * L * 128);
  const char* vp2 = (const char*)(vt_buf + (size_t)bh * 128 * L);

  bf16x8 qf[8];
  {
    const unsigned short* qr = qp + (size_t)(qbase + wid * 32 + l31) * 128 + lhi2 * 8;
#pragma unroll
    for (int kk = 0; kk < 8; kk++)
      qf[kk] = *(const bf16x8*)(qr + kk * 16);
  }

  // K staging (glds16, pre-swizzled source — rule #21)
  const char* kgp[4];
  int kdst[4];
#pragma unroll
  for (int i = 0; i < 4; i++){
    int c = wid * 4 + i;
    int row = c * 4 + (lane >> 4);
    int col = ((lane & 15) * 16) ^ ((row & 7) << 4);
    kgp[i] = kp2 + row * 256 + col;
    kdst[i] = c * 1024;
  }
  auto stage = [&](int kt, int buf){
    char* bK = (char*)lK[buf];
#pragma unroll
    for (int i = 0; i < 4; i++)
      glds16(kgp[i] + kt * 16384, bK + kdst[i]);
  };

  // V direct-read base: V^T[e = nf*32 + l31][key = kt*64 + kk2*16 + lhi2*8 + j]
  // byte addr = vp2 + e*4096 + kt*128 + kk2*32 + lhi2*16  (16 B contiguous)
  const char* vgb = vp2 + (size_t)l31 * 4096 + lhi2 * 16;

  f32x16 oacc[4];
#pragma unroll
  for (int nf = 0; nf < 4; nf++)
#pragma unroll
    for (int j = 0; j < 16; j++) oacc[nf][j] = 0.f;
  float m = -1e30f, ml2 = 0.f, lsum = 0.f;

  stage(0, 0);
  __syncthreads();
  int cur = 0;
  for (int kt = 0; kt < NT; ++kt){
    if (kt + 1 < NT) stage(kt + 1, cur ^ 1);
    const char* cK = (const char*)lK[cur];

    f32x16 sf[2];
#pragma unroll
    for (int mf = 0; mf < 2; mf++)
#pragma unroll
      for (int j = 0; j < 16; j++) sf[mf][j] = 0.f;
    __builtin_amdgcn_s_setprio(1);
#pragma unroll
    for (int kk = 0; kk < 8; kk++){
#pragma unroll
      for (int mf = 0; mf < 2; mf++){
        int byte = ((l31 * 256 + kk * 32 + lhi2 * 16) ^ ((l31 & 7) << 4)) + mf * 8192;
        bf16x8 kf = *(const bf16x8*)(cK + byte);
        sf[mf] = mfma32(kf, qf[kk], sf[mf]);
      }
    }
    __builtin_amdgcn_s_setprio(0);

    // row max: v_max3-friendly tree (T17)
    float pm[8];
#pragma unroll
    for (int g = 0; g < 8; g++){
      const float* s = (const float*)&sf[g >> 2] + (g & 3) * 4;
      pm[g] = fmaxf(max3f(s[0], s[1], s[2]), s[3]);
    }
    float tm = max3f(max3f(pm[0], pm[1], pm[2]),
                     max3f(pm[3], pm[4], pm[5]),
                     fmaxf(pm[6], pm[7]));
    tm = fmaxf(tm, __shfl_xor(tm, 32, 64));

    if (!__all(tm <= m + 8.0f)){
      float mn = fmaxf(m, tm);
      float alpha = __builtin_exp2f((m - mn) * LOG2E);
      m = mn; ml2 = mn * LOG2E;
      lsum *= alpha;
#pragma unroll
      for (int reg = 0; reg < 16; reg++){
        int row = (reg & 3) + 8 * (reg >> 2) + 4 * lhi2;
        float ar = __shfl(alpha, row | (lane & 32), 64);
#pragma unroll
        for (int nf = 0; nf < 4; nf++) oacc[nf][reg] *= ar;
      }
    }

    float pex[2][16];
    float rs = 0.f;
#pragma unroll
    for (int mf = 0; mf < 2; mf++)
#pragma unroll
      for (int j = 0; j < 16; j++){
        float p = __builtin_exp2f(__builtin_fmaf(sf[mf][j], LOG2E, -ml2));
        pex[mf][j] = p; rs += p;
      }
    rs += __shfl_xor(rs, 32, 64);
    lsum += rs;

    unsigned W[2][4][2];
#pragma unroll
    for (int mf = 0; mf < 2; mf++)
#pragma unroll
      for (int g = 0; g < 4; g++)
#pragma unroll
        for (int h = 0; h < 2; h++)
          W[mf][g][h] = (unsigned)f2bf(pex[mf][g * 4 + 2 * h]) |
                        ((unsigned)f2bf(pex[mf][g * 4 + 2 * h + 1]) << 16);

    __builtin_amdgcn_s_setprio(1);
#pragma unroll
    for (int kk2 = 0; kk2 < 4; kk2++){
      const int mfp = kk2 >> 1, gA = 2 * (kk2 & 1), gB = gA + 1;
      unsigned A0 = W[mfp][gA][0], A1 = W[mfp][gA][1];
      unsigned B0 = W[mfp][gB][0], B1 = W[mfp][gB][1];
      unsigned own0 = lhi2 ? B0 : A0, own1 = lhi2 ? B1 : A1;
      unsigned snd0 = lhi2 ? A0 : B0, snd1 = lhi2 ? A1 : B1;
      unsigned rcv0 = (unsigned)__shfl_xor((int)snd0, 32, 64);
      unsigned rcv1 = (unsigned)__shfl_xor((int)snd1, 32, 64);
      int4v pw;
      pw.x = (int)(lhi2 ? rcv0 : own0);
      pw.y = (int)(lhi2 ? rcv1 : own1);
      pw.z = (int)(lhi2 ? own0 : rcv0);
      pw.w = (int)(lhi2 ? own1 : rcv1);
      bf16x8 pa = __builtin_bit_cast(bf16x8, pw);
#pragma unroll
      for (int nf = 0; nf < 4; nf++){
        bf16x8 vb = *(const bf16x8*)(vgb + (size_t)nf * 131072 + kt * 128 + kk2 * 32);
        oacc[nf] = mfma32(pa, vb, oacc[nf]);
      }
    }
    __builtin_amdgcn_s_setprio(0);

    __syncthreads();   // drains glds (vmcnt) + retires all reads of cur
    cur ^= 1;
  }

  const int b = bh >> 4, h = bh & 15;
  float rl = 1.0f / lsum;
#pragma unroll
  for (int reg = 0; reg < 16; reg++){
    int row = (reg & 3) + 8 * (reg >> 2) + 4 * lhi2;
    float rr = __shfl(rl, row | (lane & 32), 64);
    size_t base = ((size_t)(b * L + qbase + wid * 32 + row)) * 2048 + h * 128 + l31;
#pragma unroll
    for (int nf = 0; nf < 4; nf++)
      attn_out[base + nf * 32] = f2b(oacc[nf][reg] * rr);
  }
}

extern "C" void kernel_launch(void* const* d_in, const int* in_sizes, int n_in,
                              void* d_out, int out_size, void* d_ws, size_t ws_size,
                              hipStream_t stream) {
  const float* x     = (const float*)d_in[0];
  const float* w_qkv = (const float*)d_in[1];
  const float* b_qkv = (const float*)d_in[2];
  const float* w_out = (const float*)d_in[3];
  const float* b_out = (const float*)d_in[4];
  float* out = (float*)d_out;

  unsigned short* ws = (unsigned short*)d_ws;
  unsigned short* xb    = ws;                               // 4096*2048
  unsigned short* wqkvT = xb    + (size_t)4096 * 2048;      // 6144*2048
  unsigned short* woutT = wqkvT + (size_t)6144 * 2048;      // 2048*2048
  unsigned short* qb    = woutT + (size_t)2048 * 2048;      // [2,16,2048,128]
  unsigned short* kb    = qb    + (size_t)2 * 16 * 2048 * 128;
  unsigned short* vtb   = kb    + (size_t)2 * 16 * 2048 * 128;  // [2,16,128,2048]
  unsigned short* attnb = vtb   + (size_t)2 * 16 * 2048 * 128;  // 4096*2048

  cast_bf16_kernel<<<2048, 256, 0, stream>>>((const float4*)x, (us4*)xb, (4096 * 2048) / 4);
  transpose2_kernel<<<dim3(128, 32), 256, 0, stream>>>(w_qkv, wqkvT, w_out, woutT);
  gemm_kernel<0><<<dim3(32, 48), 512, 0, stream>>>(xb, wqkvT, b_qkv, qb, kb, vtb, nullptr);
  attn_kernel<<<dim3(16, 32), 256, 0, stream>>>(qb, kb, vtb, attnb);
  gemm_kernel<1><<<dim3(32, 16), 512, 0, stream>>>(attnb, woutT, b_out, nullptr, nullptr, nullptr, out);
}

// Round 14
// 280.732 us; speedup vs baseline: 1.3259x; 1.3259x over previous
//
#include <hip/hip_runtime.h>

typedef __attribute__((ext_vector_type(8))) short bf16x8;
typedef __attribute__((ext_vector_type(4))) float f32x4;
typedef __attribute__((ext_vector_type(16))) float f32x16;
typedef __attribute__((ext_vector_type(4))) int int4v;
typedef __attribute__((ext_vector_type(4))) unsigned short us4;

#define LOG2E 1.4426950408889634f

__device__ __forceinline__ unsigned short f2b(float f){
  unsigned u = __builtin_bit_cast(unsigned, f);
  u = (u + 0x7fffu + ((u >> 16) & 1u)) >> 16;
  return (unsigned short)u;
}
// round-to-nearest (ties up) — 0.5 ulp, 2 VALU ops
__device__ __forceinline__ unsigned short f2bf(float f){
  unsigned u = __builtin_bit_cast(unsigned, f);
  return (unsigned short)((u + 0x8000u) >> 16);
}

__device__ __forceinline__ f32x4 mfma16(bf16x8 a, bf16x8 b, f32x4 c){
  return __builtin_amdgcn_mfma_f32_16x16x32_bf16(a, b, c, 0, 0, 0);
}
__device__ __forceinline__ f32x16 mfma32(bf16x8 a, bf16x8 b, f32x16 c){
  return __builtin_amdgcn_mfma_f32_32x32x16_bf16(a, b, c, 0, 0, 0);
}
// 3-input max — clang fuses nested fmaxf to v_max3_f32 (T17)
__device__ __forceinline__ float max3f(float a, float b, float c){
  return fmaxf(fmaxf(a, b), c);
}

typedef const __attribute__((address_space(1))) void* gas_t;
typedef __attribute__((address_space(3))) void* las_t;
__device__ __forceinline__ void glds16(const void* g, void* l){
  __builtin_amdgcn_global_load_lds((gas_t)g, (las_t)l, 16, 0, 0);
}

// ---------------- cast fp32 -> bf16 (vectorized) ----------------
__global__ __launch_bounds__(256) void cast_bf16_kernel(const float4* __restrict__ in,
                                                        us4* __restrict__ out, int n4){
  int i = blockIdx.x * 256 + threadIdx.x;
  int stride = gridDim.x * 256;
  for (; i < n4; i += stride){
    float4 v = in[i];
    us4 o; o.x = f2b(v.x); o.y = f2b(v.y); o.z = f2b(v.z); o.w = f2b(v.w);
    out[i] = o;
  }
}

// ------ merged transpose+cast for both weights: in[R][C] fp32 -> out[C][R] bf16 ----
__global__ __launch_bounds__(256) void transpose2_kernel(const float* __restrict__ in0,
                                                         unsigned short* __restrict__ out0,
                                                         const float* __restrict__ in1,
                                                         unsigned short* __restrict__ out1){
  __shared__ float tile[64][65];
  const int tid = threadIdx.x;
  const bool first = blockIdx.x < 96;
  const float* in = first ? in0 : in1;
  unsigned short* out = first ? out0 : out1;
  const int C = first ? 6144 : 2048;
  const int R = 2048;
  const int bx = first ? blockIdx.x : blockIdx.x - 96;
  const int c0 = bx * 64, r0 = blockIdx.y * 64;
#pragma unroll
  for (int p = 0; p < 4; p++){
    int idx = p * 1024 + tid * 4;
    int rr = idx >> 6, cc = idx & 63;
    float4 v = *(const float4*)(in + (size_t)(r0 + rr) * C + (c0 + cc));
    tile[rr][cc+0] = v.x; tile[rr][cc+1] = v.y; tile[rr][cc+2] = v.z; tile[rr][cc+3] = v.w;
  }
  __syncthreads();
#pragma unroll
  for (int p = 0; p < 4; p++){
    int idx = p * 1024 + tid * 4;
    int crow = idx >> 6, rcol = idx & 63;
    us4 o;
    o.x = f2b(tile[rcol+0][crow]); o.y = f2b(tile[rcol+1][crow]);
    o.z = f2b(tile[rcol+2][crow]); o.w = f2b(tile[rcol+3][crow]);
    *(us4*)(out + (size_t)(c0 + crow) * R + (r0 + rcol)) = o;
  }
}

// ------- bf16 GEMM (R10: 128^2 tile, 512-thr wave split): C = A*BT^T + bias -------
// BK=64, 2 LDS buffers (64 KB -> 2 blk/CU => 16 waves/CU), glds16 staging w/
// pre-swizzled global source (rule #21), single __syncthreads per K-step.
// 8 waves 2x4: wave owns 64x32 output (4 mf x 2 nf), 16 MFMA/step.
template<int MODE>
__global__ __launch_bounds__(512, 4) void gemm_kernel(
    const unsigned short* __restrict__ A,
    const unsigned short* __restrict__ BT,
    const float* __restrict__ bias,
    unsigned short* __restrict__ qb,
    unsigned short* __restrict__ kb,
    unsigned short* __restrict__ vtb,
    float* __restrict__ outp)
{
  constexpr int K = 2048;
  constexpr int NT = K / 64;
  __shared__ short lA[2][128 * 64];
  __shared__ short lB[2][128 * 64];
  const int tid = threadIdx.x, lane = tid & 63, wid = tid >> 6;
  const int l16 = lane & 15, lhi = lane >> 4;
  const int wm = wid >> 2, wn = wid & 3;
  const int bm = blockIdx.x, bn = blockIdx.y;

  const char* Abase = (const char*)(A + (size_t)bm * 128 * K);
  const char* Bbase = (const char*)(BT + (size_t)bn * 128 * K);

  // staging: chunk c = wid*2 + j (1 KB each, 16 chunks per operand)
  const char* agp[2]; const char* bgp[2];
  int dst[2];
#pragma unroll
  for (int j = 0; j < 2; j++){
    int c = wid * 2 + j;
    int row = c * 8 + (lane >> 3);
    int col = ((lane & 7) * 16) ^ ((lane >> 3) << 4);   // row&7 == lane>>3
    agp[j] = Abase + (size_t)row * (K * 2) + col;       // + kt*128
    bgp[j] = Bbase + (size_t)row * (K * 2) + col;
    dst[j] = c * 1024;                   // HW adds lane*16
  }

  auto stage = [&](int kt, int buf){
    char* bA = (char*)lA[buf]; char* bB = (char*)lB[buf];
#pragma unroll
    for (int j = 0; j < 2; j++){
      glds16(agp[j] + kt * 128, bA + dst[j]);
      glds16(bgp[j] + kt * 128, bB + dst[j]);
    }
  };

  f32x4 acc[4][2];
  f32x4 z = {0.f, 0.f, 0.f, 0.f};
#pragma unroll
  for (int i = 0; i < 4; i++)
#pragma unroll
    for (int j = 0; j < 2; j++) acc[i][j] = z;

  stage(0, 0);
  __syncthreads();
  int cur = 0;
  for (int kt = 0; kt < NT; ++kt){
    if (kt + 1 < NT) stage(kt + 1, cur ^ 1);   // prefetch into cur^1
#pragma unroll
    for (int kk = 0; kk < 2; kk++){
      bf16x8 af[4], bfr[2];
#pragma unroll
      for (int mf = 0; mf < 4; mf++){
        int row = wm * 64 + mf * 16 + l16;
        int byte = (row * 128 + kk * 64 + lhi * 16) ^ ((row & 7) << 4);
        af[mf] = *(const bf16x8*)((const char*)lA[cur] + byte);
      }
#pragma unroll
      for (int nf = 0; nf < 2; nf++){
        int row = wn * 32 + nf * 16 + l16;
        int byte = (row * 128 + kk * 64 + lhi * 16) ^ ((row & 7) << 4);
        bfr[nf] = *(const bf16x8*)((const char*)lB[cur] + byte);
      }
      __builtin_amdgcn_s_setprio(1);
#pragma unroll
      for (int mf = 0; mf < 4; mf++)
#pragma unroll
        for (int nf = 0; nf < 2; nf++)
          acc[mf][nf] = mfma16(af[mf], bfr[nf], acc[mf][nf]);
      __builtin_amdgcn_s_setprio(0);
    }
    __syncthreads();   // drains vmcnt (glds of cur^1 complete) + retires reads of cur
    cur ^= 1;
  }

  const int row0 = bm * 128 + wm * 64;
  const int col0 = bn * 128 + wn * 32;
  if (MODE == 0){
#pragma unroll
    for (int nf = 0; nf < 2; nf++){
      int colb = col0 + nf * 16;
      float bv = bias[colb + l16];
      int which = colb >> 11;
      int h = (colb >> 7) & 15;
      int e = (colb & 127) + l16;
#pragma unroll
      for (int mf = 0; mf < 4; mf++){
#pragma unroll
        for (int r = 0; r < 4; r++){
          int row = row0 + mf * 16 + lhi * 4 + r;
          int b = row >> 11, t = row & 2047;
          float v = acc[mf][nf][r] + bv;
          size_t bh = (size_t)(b * 16 + h);
          if (which == 0)      qb[(bh * 2048 + t) * 128 + e] = f2b(v * 0.08838834764831845f);
          else if (which == 1) kb[(bh * 2048 + t) * 128 + e] = f2b(v);
          else                 vtb[(bh * 128 + e) * 2048 + t] = f2b(v);
        }
      }
    }
  } else {
#pragma unroll
    for (int nf = 0; nf < 2; nf++){
      int col = col0 + nf * 16 + l16;
      float bv = bias[col];
#pragma unroll
      for (int mf = 0; mf < 4; mf++){
#pragma unroll
        for (int r = 0; r < 4; r++){
          int row = row0 + mf * 16 + lhi * 4 + r;
          outp[(size_t)row * 2048 + col] = acc[mf][nf][r] + bv;
        }
      }
    }
  }
}

// ---------------- flash attention v2 (R10): 32x32 MFMA, swapped QK^T,
//                  in-reg softmax, K+V^T LDS dbuf, glds16 staging ----------------
__global__ __launch_bounds__(256, 2) void attn_kernel(
    const unsigned short* __restrict__ q_buf,
    const unsigned short* __restrict__ k_buf,
    const unsigned short* __restrict__ vt_buf,
    unsigned short* __restrict__ attn_out)
{
  constexpr int L = 2048, NT = L / 64;
  __shared__ short lK[2][64 * 128];   // [key][e] rows 256 B, swizzled ^((key&7)<<4)
  __shared__ short lVT[2][128 * 64];  // [e][key] rows 128 B, swizzled ^((e&7)<<4)
  const int tid = threadIdx.x, lane = tid & 63, wid = tid >> 6;
  const int l31 = lane & 31, lhi2 = lane >> 5;

  const int d = blockIdx.y * 16 + blockIdx.x;
  const int bh = (d & 7) + 8 * ((d >> 3) & 3);
  const int qi = d >> 5;
  const int qbase = qi * 128;

  const unsigned short* qp = q_buf + (size_t)bh * L * 128;
  const char* kp2 = (const char*)(k_buf + (size_t)bh * L * 128);
  const char* vp2 = (const char*)(vt_buf + (size_t)bh * 128 * L);

  bf16x8 qf[8];
  {
    const unsigned short* qr = qp + (size_t)(qbase + wid * 32 + l31) * 128 + lhi2 * 8;
#pragma unroll
    for (int kk = 0; kk < 8; kk++)
      qf[kk] = *(const bf16x8*)(qr + kk * 16);
  }

  const char* kgp[4]; const char* vgp[4];
  int kdst[4], vdst[4];
#pragma unroll
  for (int i = 0; i < 4; i++){
    int c = wid * 4 + i;
    { int row = c * 4 + (lane >> 4);
      int col = ((lane & 15) * 16) ^ ((row & 7) << 4);
      kgp[i] = kp2 + row * 256 + col;
      kdst[i] = c * 1024; }
    { int e = c * 8 + (lane >> 3);
      int col = ((lane & 7) * 16) ^ ((e & 7) << 4);
      vgp[i] = vp2 + (size_t)e * 4096 + col;
      vdst[i] = c * 1024; }
  }

  auto stage = [&](int kt, int buf){
    char* bK = (char*)lK[buf]; char* bV = (char*)lVT[buf];
#pragma unroll
    for (int i = 0; i < 4; i++){
      glds16(kgp[i] + kt * 16384, bK + kdst[i]);
      glds16(vgp[i] + (size_t)kt * 128, bV + vdst[i]);
    }
  };

  f32x16 oacc[4];
#pragma unroll
  for (int nf = 0; nf < 4; nf++)
#pragma unroll
    for (int j = 0; j < 16; j++) oacc[nf][j] = 0.f;
  float m = -1e30f, ml2 = 0.f, lsum = 0.f;

  stage(0, 0);
  __syncthreads();
  int cur = 0;
  for (int kt = 0; kt < NT; ++kt){
    if (kt + 1 < NT) stage(kt + 1, cur ^ 1);
    const char* cK = (const char*)lK[cur];
    const char* cV = (const char*)lVT[cur];

    f32x16 sf[2];
#pragma unroll
    for (int mf = 0; mf < 2; mf++)
#pragma unroll
      for (int j = 0; j < 16; j++) sf[mf][j] = 0.f;
    __builtin_amdgcn_s_setprio(1);
#pragma unroll
    for (int kk = 0; kk < 8; kk++){
#pragma unroll
      for (int mf = 0; mf < 2; mf++){
        int byte = ((l31 * 256 + kk * 32 + lhi2 * 16) ^ ((l31 & 7) << 4)) + mf * 8192;
        bf16x8 kf = *(const bf16x8*)(cK + byte);
        sf[mf] = mfma32(kf, qf[kk], sf[mf]);
      }
    }
    __builtin_amdgcn_s_setprio(0);

    // row max: v_max3-friendly tree (T17)
    float pm[8];
#pragma unroll
    for (int g = 0; g < 8; g++){
      const float* s = (const float*)&sf[g >> 2] + (g & 3) * 4;
      pm[g] = fmaxf(max3f(s[0], s[1], s[2]), s[3]);
    }
    float tm = max3f(max3f(pm[0], pm[1], pm[2]),
                     max3f(pm[3], pm[4], pm[5]),
                     fmaxf(pm[6], pm[7]));
    tm = fmaxf(tm, __shfl_xor(tm, 32, 64));

    if (!__all(tm <= m + 8.0f)){
      float mn = fmaxf(m, tm);
      float alpha = __builtin_exp2f((m - mn) * LOG2E);
      m = mn; ml2 = mn * LOG2E;
      lsum *= alpha;
#pragma unroll
      for (int reg = 0; reg < 16; reg++){
        int row = (reg & 3) + 8 * (reg >> 2) + 4 * lhi2;
        float ar = __shfl(alpha, row | (lane & 32), 64);
#pragma unroll
        for (int nf = 0; nf < 4; nf++) oacc[nf][reg] *= ar;
      }
    }

    float pex[2][16];
    float rs = 0.f;
#pragma unroll
    for (int mf = 0; mf < 2; mf++)
#pragma unroll
      for (int j = 0; j < 16; j++){
        float p = __builtin_exp2f(__builtin_fmaf(sf[mf][j], LOG2E, -ml2));
        pex[mf][j] = p; rs += p;
      }
    rs += __shfl_xor(rs, 32, 64);
    lsum += rs;

    unsigned W[2][4][2];
#pragma unroll
    for (int mf = 0; mf < 2; mf++)
#pragma unroll
      for (int g = 0; g < 4; g++)
#pragma unroll
        for (int h = 0; h < 2; h++)
          W[mf][g][h] = (unsigned)f2bf(pex[mf][g * 4 + 2 * h]) |
                        ((unsigned)f2bf(pex[mf][g * 4 + 2 * h + 1]) << 16);

    __builtin_amdgcn_s_setprio(1);
#pragma unroll
    for (int kk2 = 0; kk2 < 4; kk2++){
      const int mfp = kk2 >> 1, gA = 2 * (kk2 & 1), gB = gA + 1;
      unsigned A0 = W[mfp][gA][0], A1 = W[mfp][gA][1];
      unsigned B0 = W[mfp][gB][0], B1 = W[mfp][gB][1];
      unsigned own0 = lhi2 ? B0 : A0, own1 = lhi2 ? B1 : A1;
      unsigned snd0 = lhi2 ? A0 : B0, snd1 = lhi2 ? A1 : B1;
      unsigned rcv0 = (unsigned)__shfl_xor((int)snd0, 32, 64);
      unsigned rcv1 = (unsigned)__shfl_xor((int)snd1, 32, 64);
      int4v pw;
      pw.x = (int)(lhi2 ? rcv0 : own0);
      pw.y = (int)(lhi2 ? rcv1 : own1);
      pw.z = (int)(lhi2 ? own0 : rcv0);
      pw.w = (int)(lhi2 ? own1 : rcv1);
      bf16x8 pa = __builtin_bit_cast(bf16x8, pw);
#pragma unroll
      for (int nf = 0; nf < 4; nf++){
        int byte = ((l31 * 128 + kk2 * 32 + lhi2 * 16) ^ ((l31 & 7) << 4)) + nf * 4096;
        bf16x8 vb = *(const bf16x8*)(cV + byte);
        oacc[nf] = mfma32(pa, vb, oacc[nf]);
      }
    }
    __builtin_amdgcn_s_setprio(0);

    __syncthreads();
    cur ^= 1;
  }

  const int b = bh >> 4, h = bh & 15;
  float rl = 1.0f / lsum;
#pragma unroll
  for (int reg = 0; reg < 16; reg++){
    int row = (reg & 3) + 8 * (reg >> 2) + 4 * lhi2;
    float rr = __shfl(rl, row | (lane & 32), 64);
    size_t base = ((size_t)(b * L + qbase + wid * 32 + row)) * 2048 + h * 128 + l31;
#pragma unroll
    for (int nf = 0; nf < 4; nf++)
      attn_out[base + nf * 32] = f2b(oacc[nf][reg] * rr);
  }
}

extern "C" void kernel_launch(void* const* d_in, const int* in_sizes, int n_in,
                              void* d_out, int out_size, void* d_ws, size_t ws_size,
                              hipStream_t stream) {
  const float* x     = (const float*)d_in[0];
  const float* w_qkv = (const float*)d_in[1];
  const float* b_qkv = (const float*)d_in[2];
  const float* w_out = (const float*)d_in[3];
  const float* b_out = (const float*)d_in[4];
  float* out = (float*)d_out;

  unsigned short* ws = (unsigned short*)d_ws;
  unsigned short* xb    = ws;                               // 4096*2048
  unsigned short* wqkvT = xb    + (size_t)4096 * 2048;      // 6144*2048
  unsigned short* woutT = wqkvT + (size_t)6144 * 2048;      // 2048*2048
  unsigned short* qb    = woutT + (size_t)2048 * 2048;      // [2,16,2048,128]
  unsigned short* kb    = qb    + (size_t)2 * 16 * 2048 * 128;
  unsigned short* vtb   = kb    + (size_t)2 * 16 * 2048 * 128;  // [2,16,128,2048]
  unsigned short* attnb = vtb   + (size_t)2 * 16 * 2048 * 128;  // 4096*2048

  cast_bf16_kernel<<<2048, 256, 0, stream>>>((const float4*)x, (us4*)xb, (4096 * 2048) / 4);
  transpose2_kernel<<<dim3(128, 32), 256, 0, stream>>>(w_qkv, wqkvT, w_out, woutT);
  gemm_kernel<0><<<dim3(32, 48), 512, 0, stream>>>(xb, wqkvT, b_qkv, qb, kb, vtb, nullptr);
  attn_kernel<<<dim3(16, 32), 256, 0, stream>>>(qb, kb, vtb, attnb);
  gemm_kernel<1><<<dim3(32, 16), 512, 0, stream>>>(attnb, woutT, b_out, nullptr, nullptr, nullptr, out);
}

// Round 15
// 273.816 us; speedup vs baseline: 1.3594x; 1.0253x over previous
//
#include <hip/hip_runtime.h>

typedef __attribute__((ext_vector_type(8))) short bf16x8;
typedef __attribute__((ext_vector_type(4))) float f32x4;
typedef __attribute__((ext_vector_type(16))) float f32x16;
typedef __attribute__((ext_vector_type(4))) int int4v;
typedef __attribute__((ext_vector_type(4))) unsigned short us4;

#define LOG2E 1.4426950408889634f

__device__ __forceinline__ unsigned short f2b(float f){
  unsigned u = __builtin_bit_cast(unsigned, f);
  u = (u + 0x7fffu + ((u >> 16) & 1u)) >> 16;
  return (unsigned short)u;
}
// round-to-nearest (ties up) — 0.5 ulp, 2 VALU ops
__device__ __forceinline__ unsigned short f2bf(float f){
  unsigned u = __builtin_bit_cast(unsigned, f);
  return (unsigned short)((u + 0x8000u) >> 16);
}

__device__ __forceinline__ f32x4 mfma16(bf16x8 a, bf16x8 b, f32x4 c){
  return __builtin_amdgcn_mfma_f32_16x16x32_bf16(a, b, c, 0, 0, 0);
}
__device__ __forceinline__ f32x16 mfma32(bf16x8 a, bf16x8 b, f32x16 c){
  return __builtin_amdgcn_mfma_f32_32x32x16_bf16(a, b, c, 0, 0, 0);
}
// 3-input max — clang fuses nested fmaxf to v_max3_f32 (T17)
__device__ __forceinline__ float max3f(float a, float b, float c){
  return fmaxf(fmaxf(a, b), c);
}

typedef const __attribute__((address_space(1))) void* gas_t;
typedef __attribute__((address_space(3))) void* las_t;
__device__ __forceinline__ void glds16(const void* g, void* l){
  __builtin_amdgcn_global_load_lds((gas_t)g, (las_t)l, 16, 0, 0);
}

// ---------------- cast fp32 -> bf16 (vectorized) ----------------
__global__ __launch_bounds__(256) void cast_bf16_kernel(const float4* __restrict__ in,
                                                        us4* __restrict__ out, int n4){
  int i = blockIdx.x * 256 + threadIdx.x;
  int stride = gridDim.x * 256;
  for (; i < n4; i += stride){
    float4 v = in[i];
    us4 o; o.x = f2b(v.x); o.y = f2b(v.y); o.z = f2b(v.z); o.w = f2b(v.w);
    out[i] = o;
  }
}

// ------ merged transpose+cast for both weights: in[R][C] fp32 -> out[C][R] bf16 ----
__global__ __launch_bounds__(256) void transpose2_kernel(const float* __restrict__ in0,
                                                         unsigned short* __restrict__ out0,
                                                         const float* __restrict__ in1,
                                                         unsigned short* __restrict__ out1){
  __shared__ float tile[64][65];
  const int tid = threadIdx.x;
  const bool first = blockIdx.x < 96;
  const float* in = first ? in0 : in1;
  unsigned short* out = first ? out0 : out1;
  const int C = first ? 6144 : 2048;
  const int R = 2048;
  const int bx = first ? blockIdx.x : blockIdx.x - 96;
  const int c0 = bx * 64, r0 = blockIdx.y * 64;
#pragma unroll
  for (int p = 0; p < 4; p++){
    int idx = p * 1024 + tid * 4;
    int rr = idx >> 6, cc = idx & 63;
    float4 v = *(const float4*)(in + (size_t)(r0 + rr) * C + (c0 + cc));
    tile[rr][cc+0] = v.x; tile[rr][cc+1] = v.y; tile[rr][cc+2] = v.z; tile[rr][cc+3] = v.w;
  }
  __syncthreads();
#pragma unroll
  for (int p = 0; p < 4; p++){
    int idx = p * 1024 + tid * 4;
    int crow = idx >> 6, rcol = idx & 63;
    us4 o;
    o.x = f2b(tile[rcol+0][crow]); o.y = f2b(tile[rcol+1][crow]);
    o.z = f2b(tile[rcol+2][crow]); o.w = f2b(tile[rcol+3][crow]);
    *(us4*)(out + (size_t)(c0 + crow) * R + (r0 + rcol)) = o;
  }
}

// ------- bf16 GEMM (R10: 128^2 tile, 512-thr wave split): C = A*BT^T + bias -------
// BK=64, 2 LDS buffers (64 KB -> 2 blk/CU => 16 waves/CU), glds16 staging w/
// pre-swizzled global source (rule #21), single __syncthreads per K-step.
// 8 waves 2x4: wave owns 64x32 output (4 mf x 2 nf), 16 MFMA/step.
// MODE0 v-blocks (bn>=32): epilogue transposes through LDS so the v^T write is
// coalesced 16B rows instead of a 64-lane 4KB-stride 2B scatter.
template<int MODE>
__global__ __launch_bounds__(512, 4) void gemm_kernel(
    const unsigned short* __restrict__ A,
    const unsigned short* __restrict__ BT,
    const float* __restrict__ bias,
    unsigned short* __restrict__ qb,
    unsigned short* __restrict__ kb,
    unsigned short* __restrict__ vtb,
    float* __restrict__ outp)
{
  constexpr int K = 2048;
  constexpr int NT = K / 64;
  __shared__ short lA[2][128 * 64];
  __shared__ short lB[2][128 * 64];
  const int tid = threadIdx.x, lane = tid & 63, wid = tid >> 6;
  const int l16 = lane & 15, lhi = lane >> 4;
  const int wm = wid >> 2, wn = wid & 3;
  const int bm = blockIdx.x, bn = blockIdx.y;

  const char* Abase = (const char*)(A + (size_t)bm * 128 * K);
  const char* Bbase = (const char*)(BT + (size_t)bn * 128 * K);

  // staging: chunk c = wid*2 + j (1 KB each, 16 chunks per operand)
  const char* agp[2]; const char* bgp[2];
  int dst[2];
#pragma unroll
  for (int j = 0; j < 2; j++){
    int c = wid * 2 + j;
    int row = c * 8 + (lane >> 3);
    int col = ((lane & 7) * 16) ^ ((lane >> 3) << 4);   // row&7 == lane>>3
    agp[j] = Abase + (size_t)row * (K * 2) + col;       // + kt*128
    bgp[j] = Bbase + (size_t)row * (K * 2) + col;
    dst[j] = c * 1024;                   // HW adds lane*16
  }

  auto stage = [&](int kt, int buf){
    char* bA = (char*)lA[buf]; char* bB = (char*)lB[buf];
#pragma unroll
    for (int j = 0; j < 2; j++){
      glds16(agp[j] + kt * 128, bA + dst[j]);
      glds16(bgp[j] + kt * 128, bB + dst[j]);
    }
  };

  f32x4 acc[4][2];
  f32x4 z = {0.f, 0.f, 0.f, 0.f};
#pragma unroll
  for (int i = 0; i < 4; i++)
#pragma unroll
    for (int j = 0; j < 2; j++) acc[i][j] = z;

  stage(0, 0);
  __syncthreads();
  int cur = 0;
  for (int kt = 0; kt < NT; ++kt){
    if (kt + 1 < NT) stage(kt + 1, cur ^ 1);   // prefetch into cur^1
#pragma unroll
    for (int kk = 0; kk < 2; kk++){
      bf16x8 af[4], bfr[2];
#pragma unroll
      for (int mf = 0; mf < 4; mf++){
        int row = wm * 64 + mf * 16 + l16;
        int byte = (row * 128 + kk * 64 + lhi * 16) ^ ((row & 7) << 4);
        af[mf] = *(const bf16x8*)((const char*)lA[cur] + byte);
      }
#pragma unroll
      for (int nf = 0; nf < 2; nf++){
        int row = wn * 32 + nf * 16 + l16;
        int byte = (row * 128 + kk * 64 + lhi * 16) ^ ((row & 7) << 4);
        bfr[nf] = *(const bf16x8*)((const char*)lB[cur] + byte);
      }
      __builtin_amdgcn_s_setprio(1);
#pragma unroll
      for (int mf = 0; mf < 4; mf++)
#pragma unroll
        for (int nf = 0; nf < 2; nf++)
          acc[mf][nf] = mfma16(af[mf], bfr[nf], acc[mf][nf]);
      __builtin_amdgcn_s_setprio(0);
    }
    __syncthreads();   // drains vmcnt (glds of cur^1 complete) + retires reads of cur
    cur ^= 1;
  }

  const int row0 = bm * 128 + wm * 64;
  const int col0 = bn * 128 + wn * 32;
  if (MODE == 0){
    if (bn < 32){
      // q / k blocks: direct coalesced element writes (which is 0 or 1)
#pragma unroll
      for (int nf = 0; nf < 2; nf++){
        int colb = col0 + nf * 16;
        float bv = bias[colb + l16];
        int which = colb >> 11;
        int h = (colb >> 7) & 15;
        int e = (colb & 127) + l16;
#pragma unroll
        for (int mf = 0; mf < 4; mf++){
#pragma unroll
          for (int r = 0; r < 4; r++){
            int row = row0 + mf * 16 + lhi * 4 + r;
            int b = row >> 11, t = row & 2047;
            float v = acc[mf][nf][r] + bv;
            size_t bh = (size_t)(b * 16 + h);
            if (which == 0) qb[(bh * 2048 + t) * 128 + e] = f2b(v * 0.08838834764831845f);
            else            kb[(bh * 2048 + t) * 128 + e] = f2b(v);
          }
        }
      }
    } else {
      // v blocks: transpose through LDS (reuse lA; K-loop's final barrier freed it).
      // LDS tile [e][t]: byte = e*256 + ((t*2) ^ ((e&7)<<4))  (rule #21: same XOR
      // on write and read; write conflicts 2-way = free).
      char* tb = (char*)lA;
      const int h = bn - 32, b = bm >> 4, t0 = (bm & 15) * 128;
#pragma unroll
      for (int nf = 0; nf < 2; nf++){
        int e = wn * 32 + nf * 16 + l16;
        float bv = bias[4096 + h * 128 + e];
#pragma unroll
        for (int mf = 0; mf < 4; mf++){
#pragma unroll
          for (int r = 0; r < 4; r++){
            int t = wm * 64 + mf * 16 + lhi * 4 + r;
            int byte = e * 256 + ((t * 2) ^ ((e & 7) << 4));
            *(unsigned short*)(tb + byte) = f2b(acc[mf][nf][r] + bv);
          }
        }
      }
      __syncthreads();
      // coalesced out: thread -> row ep, 32 t's (4 x 16B chunks)
      const int ep = tid >> 2, tq = (tid & 3) * 32;
      unsigned short* dstp = vtb + ((size_t)(b * 16 + h) * 128 + ep) * 2048 + t0 + tq;
      const char* srow = tb + ep * 256;
#pragma unroll
      for (int c = 0; c < 4; c++){
        int t = tq + c * 8;
        int4v v4 = *(const int4v*)(srow + ((t * 2) ^ ((ep & 7) << 4)));
        *(int4v*)(dstp + c * 8) = v4;
      }
    }
  } else {
#pragma unroll
    for (int nf = 0; nf < 2; nf++){
      int col = col0 + nf * 16 + l16;
      float bv = bias[col];
#pragma unroll
      for (int mf = 0; mf < 4; mf++){
#pragma unroll
        for (int r = 0; r < 4; r++){
          int row = row0 + mf * 16 + lhi * 4 + r;
          outp[(size_t)row * 2048 + col] = acc[mf][nf][r] + bv;
        }
      }
    }
  }
}

// ---------------- flash attention v2 (R10): 32x32 MFMA, swapped QK^T,
//                  in-reg softmax, K+V^T LDS dbuf, glds16 staging ----------------
__global__ __launch_bounds__(256, 2) void attn_kernel(
    const unsigned short* __restrict__ q_buf,
    const unsigned short* __restrict__ k_buf,
    const unsigned short* __restrict__ vt_buf,
    unsigned short* __restrict__ attn_out)
{
  constexpr int L = 2048, NT = L / 64;
  __shared__ short lK[2][64 * 128];   // [key][e] rows 256 B, swizzled ^((key&7)<<4)
  __shared__ short lVT[2][128 * 64];  // [e][key] rows 128 B, swizzled ^((e&7)<<4)
  const int tid = threadIdx.x, lane = tid & 63, wid = tid >> 6;
  const int l31 = lane & 31, lhi2 = lane >> 5;

  const int d = blockIdx.y * 16 + blockIdx.x;
  const int bh = (d & 7) + 8 * ((d >> 3) & 3);
  const int qi = d >> 5;
  const int qbase = qi * 128;

  const unsigned short* qp = q_buf + (size_t)bh * L * 128;
  const char* kp2 = (const char*)(k_buf + (size_t)bh * L * 128);
  const char* vp2 = (const char*)(vt_buf + (size_t)bh * 128 * L);

  bf16x8 qf[8];
  {
    const unsigned short* qr = qp + (size_t)(qbase + wid * 32 + l31) * 128 + lhi2 * 8;
#pragma unroll
    for (int kk = 0; kk < 8; kk++)
      qf[kk] = *(const bf16x8*)(qr + kk * 16);
  }

  const char* kgp[4]; const char* vgp[4];
  int kdst[4], vdst[4];
#pragma unroll
  for (int i = 0; i < 4; i++){
    int c = wid * 4 + i;
    { int row = c * 4 + (lane >> 4);
      int col = ((lane & 15) * 16) ^ ((row & 7) << 4);
      kgp[i] = kp2 + row * 256 + col;
      kdst[i] = c * 1024; }
    { int e = c * 8 + (lane >> 3);
      int col = ((lane & 7) * 16) ^ ((e & 7) << 4);
      vgp[i] = vp2 + (size_t)e * 4096 + col;
      vdst[i] = c * 1024; }
  }

  auto stage = [&](int kt, int buf){
    char* bK = (char*)lK[buf]; char* bV = (char*)lVT[buf];
#pragma unroll
    for (int i = 0; i < 4; i++){
      glds16(kgp[i] + kt * 16384, bK + kdst[i]);
      glds16(vgp[i] + (size_t)kt * 128, bV + vdst[i]);
    }
  };

  f32x16 oacc[4];
#pragma unroll
  for (int nf = 0; nf < 4; nf++)
#pragma unroll
    for (int j = 0; j < 16; j++) oacc[nf][j] = 0.f;
  float m = -1e30f, ml2 = 0.f, lsum = 0.f;

  stage(0, 0);
  __syncthreads();
  int cur = 0;
  for (int kt = 0; kt < NT; ++kt){
    if (kt + 1 < NT) stage(kt + 1, cur ^ 1);
    const char* cK = (const char*)lK[cur];
    const char* cV = (const char*)lVT[cur];

    f32x16 sf[2];
#pragma unroll
    for (int mf = 0; mf < 2; mf++)
#pragma unroll
      for (int j = 0; j < 16; j++) sf[mf][j] = 0.f;
    __builtin_amdgcn_s_setprio(1);
#pragma unroll
    for (int kk = 0; kk < 8; kk++){
#pragma unroll
      for (int mf = 0; mf < 2; mf++){
        int byte = ((l31 * 256 + kk * 32 + lhi2 * 16) ^ ((l31 & 7) << 4)) + mf * 8192;
        bf16x8 kf = *(const bf16x8*)(cK + byte);
        sf[mf] = mfma32(kf, qf[kk], sf[mf]);
      }
    }
    __builtin_amdgcn_s_setprio(0);

    // row max: v_max3-friendly tree (T17)
    float pm[8];
#pragma unroll
    for (int g = 0; g < 8; g++){
      const float* s = (const float*)&sf[g >> 2] + (g & 3) * 4;
      pm[g] = fmaxf(max3f(s[0], s[1], s[2]), s[3]);
    }
    float tm = max3f(max3f(pm[0], pm[1], pm[2]),
                     max3f(pm[3], pm[4], pm[5]),
                     fmaxf(pm[6], pm[7]));
    tm = fmaxf(tm, __shfl_xor(tm, 32, 64));

    if (!__all(tm <= m + 8.0f)){
      float mn = fmaxf(m, tm);
      float alpha = __builtin_exp2f((m - mn) * LOG2E);
      m = mn; ml2 = mn * LOG2E;
      lsum *= alpha;
#pragma unroll
      for (int reg = 0; reg < 16; reg++){
        int row = (reg & 3) + 8 * (reg >> 2) + 4 * lhi2;
        float ar = __shfl(alpha, row | (lane & 32), 64);
#pragma unroll
        for (int nf = 0; nf < 4; nf++) oacc[nf][reg] *= ar;
      }
    }

    float pex[2][16];
    float rs = 0.f;
#pragma unroll
    for (int mf = 0; mf < 2; mf++)
#pragma unroll
      for (int j = 0; j < 16; j++){
        float p = __builtin_exp2f(__builtin_fmaf(sf[mf][j], LOG2E, -ml2));
        pex[mf][j] = p; rs += p;
      }
    rs += __shfl_xor(rs, 32, 64);
    lsum += rs;

    unsigned W[2][4][2];
#pragma unroll
    for (int mf = 0; mf < 2; mf++)
#pragma unroll
      for (int g = 0; g < 4; g++)
#pragma unroll
        for (int h = 0; h < 2; h++)
          W[mf][g][h] = (unsigned)f2bf(pex[mf][g * 4 + 2 * h]) |
                        ((unsigned)f2bf(pex[mf][g * 4 + 2 * h + 1]) << 16);

    __builtin_amdgcn_s_setprio(1);
#pragma unroll
    for (int kk2 = 0; kk2 < 4; kk2++){
      const int mfp = kk2 >> 1, gA = 2 * (kk2 & 1), gB = gA + 1;
      unsigned A0 = W[mfp][gA][0], A1 = W[mfp][gA][1];
      unsigned B0 = W[mfp][gB][0], B1 = W[mfp][gB][1];
      unsigned own0 = lhi2 ? B0 : A0, own1 = lhi2 ? B1 : A1;
      unsigned snd0 = lhi2 ? A0 : B0, snd1 = lhi2 ? A1 : B1;
      unsigned rcv0 = (unsigned)__shfl_xor((int)snd0, 32, 64);
      unsigned rcv1 = (unsigned)__shfl_xor((int)snd1, 32, 64);
      int4v pw;
      pw.x = (int)(lhi2 ? rcv0 : own0);
      pw.y = (int)(lhi2 ? rcv1 : own1);
      pw.z = (int)(lhi2 ? own0 : rcv0);
      pw.w = (int)(lhi2 ? own1 : rcv1);
      bf16x8 pa = __builtin_bit_cast(bf16x8, pw);
#pragma unroll
      for (int nf = 0; nf < 4; nf++){
        int byte = ((l31 * 128 + kk2 * 32 + lhi2 * 16) ^ ((l31 & 7) << 4)) + nf * 4096;
        bf16x8 vb = *(const bf16x8*)(cV + byte);
        oacc[nf] = mfma32(pa, vb, oacc[nf]);
      }
    }
    __builtin_amdgcn_s_setprio(0);

    __syncthreads();
    cur ^= 1;
  }

  const int b = bh >> 4, h = bh & 15;
  float rl = 1.0f / lsum;
#pragma unroll
  for (int reg = 0; reg < 16; reg++){
    int row = (reg & 3) + 8 * (reg >> 2) + 4 * lhi2;
    float rr = __shfl(rl, row | (lane & 32), 64);
    size_t base = ((size_t)(b * L + qbase + wid * 32 + row)) * 2048 + h * 128 + l31;
#pragma unroll
    for (int nf = 0; nf < 4; nf++)
      attn_out[base + nf * 32] = f2b(oacc[nf][reg] * rr);
  }
}

extern "C" void kernel_launch(void* const* d_in, const int* in_sizes, int n_in,
                              void* d_out, int out_size, void* d_ws, size_t ws_size,
                              hipStream_t stream) {
  const float* x     = (const float*)d_in[0];
  const float* w_qkv = (const float*)d_in[1];
  const float* b_qkv = (const float*)d_in[2];
  const float* w_out = (const float*)d_in[3];
  const float* b_out = (const float*)d_in[4];
  float* out = (float*)d_out;

  unsigned short* ws = (unsigned short*)d_ws;
  unsigned short* xb    = ws;                               // 4096*2048
  unsigned short* wqkvT = xb    + (size_t)4096 * 2048;      // 6144*2048
  unsigned short* woutT = wqkvT + (size_t)6144 * 2048;      // 2048*2048
  unsigned short* qb    = woutT + (size_t)2048 * 2048;      // [2,16,2048,128]
  unsigned short* kb    = qb    + (size_t)2 * 16 * 2048 * 128;
  unsigned short* vtb   = kb    + (size_t)2 * 16 * 2048 * 128;  // [2,16,128,2048]
  unsigned short* attnb = vtb   + (size_t)2 * 16 * 2048 * 128;  // 4096*2048

  cast_bf16_kernel<<<2048, 256, 0, stream>>>((const float4*)x, (us4*)xb, (4096 * 2048) / 4);
  transpose2_kernel<<<dim3(128, 32), 256, 0, stream>>>(w_qkv, wqkvT, w_out, woutT);
  gemm_kernel<0><<<dim3(32, 48), 512, 0, stream>>>(xb, wqkvT, b_qkv, qb, kb, vtb, nullptr);
  attn_kernel<<<dim3(16, 32), 256, 0, stream>>>(qb, kb, vtb, attnb);
  gemm_kernel<1><<<dim3(32, 16), 512, 0, stream>>>(attnb, woutT, b_out, nullptr, nullptr, nullptr, out);
}

// Round 16
// 268.728 us; speedup vs baseline: 1.3852x; 1.0189x over previous
//
#include <hip/hip_runtime.h>

typedef __attribute__((ext_vector_type(8))) short bf16x8;
typedef __attribute__((ext_vector_type(4))) float f32x4;
typedef __attribute__((ext_vector_type(16))) float f32x16;
typedef __attribute__((ext_vector_type(4))) int int4v;
typedef __attribute__((ext_vector_type(4))) unsigned short us4;

#define LOG2E 1.4426950408889634f

__device__ __forceinline__ unsigned short f2b(float f){
  unsigned u = __builtin_bit_cast(unsigned, f);
  u = (u + 0x7fffu + ((u >> 16) & 1u)) >> 16;
  return (unsigned short)u;
}
// round-to-nearest (ties up) — 0.5 ulp, 2 VALU ops
__device__ __forceinline__ unsigned short f2bf(float f){
  unsigned u = __builtin_bit_cast(unsigned, f);
  return (unsigned short)((u + 0x8000u) >> 16);
}

__device__ __forceinline__ f32x4 mfma16(bf16x8 a, bf16x8 b, f32x4 c){
  return __builtin_amdgcn_mfma_f32_16x16x32_bf16(a, b, c, 0, 0, 0);
}
__device__ __forceinline__ f32x16 mfma32(bf16x8 a, bf16x8 b, f32x16 c){
  return __builtin_amdgcn_mfma_f32_32x32x16_bf16(a, b, c, 0, 0, 0);
}
// 3-input max — clang fuses nested fmaxf to v_max3_f32 (T17)
__device__ __forceinline__ float max3f(float a, float b, float c){
  return fmaxf(fmaxf(a, b), c);
}

typedef const __attribute__((address_space(1))) void* gas_t;
typedef __attribute__((address_space(3))) void* las_t;
__device__ __forceinline__ void glds16(const void* g, void* l){
  __builtin_amdgcn_global_load_lds((gas_t)g, (las_t)l, 16, 0, 0);
}

// ---------------- cast fp32 -> bf16 (vectorized) ----------------
__global__ __launch_bounds__(256) void cast_bf16_kernel(const float4* __restrict__ in,
                                                        us4* __restrict__ out, int n4){
  int i = blockIdx.x * 256 + threadIdx.x;
  int stride = gridDim.x * 256;
  for (; i < n4; i += stride){
    float4 v = in[i];
    us4 o; o.x = f2b(v.x); o.y = f2b(v.y); o.z = f2b(v.z); o.w = f2b(v.w);
    out[i] = o;
  }
}

// ------ merged transpose+cast for both weights: in[R][C] fp32 -> out[C][R] bf16 ----
__global__ __launch_bounds__(256) void transpose2_kernel(const float* __restrict__ in0,
                                                         unsigned short* __restrict__ out0,
                                                         const float* __restrict__ in1,
                                                         unsigned short* __restrict__ out1){
  __shared__ float tile[64][65];
  const int tid = threadIdx.x;
  const bool first = blockIdx.x < 96;
  const float* in = first ? in0 : in1;
  unsigned short* out = first ? out0 : out1;
  const int C = first ? 6144 : 2048;
  const int R = 2048;
  const int bx = first ? blockIdx.x : blockIdx.x - 96;
  const int c0 = bx * 64, r0 = blockIdx.y * 64;
#pragma unroll
  for (int p = 0; p < 4; p++){
    int idx = p * 1024 + tid * 4;
    int rr = idx >> 6, cc = idx & 63;
    float4 v = *(const float4*)(in + (size_t)(r0 + rr) * C + (c0 + cc));
    tile[rr][cc+0] = v.x; tile[rr][cc+1] = v.y; tile[rr][cc+2] = v.z; tile[rr][cc+3] = v.w;
  }
  __syncthreads();
#pragma unroll
  for (int p = 0; p < 4; p++){
    int idx = p * 1024 + tid * 4;
    int crow = idx >> 6, rcol = idx & 63;
    us4 o;
    o.x = f2b(tile[rcol+0][crow]); o.y = f2b(tile[rcol+1][crow]);
    o.z = f2b(tile[rcol+2][crow]); o.w = f2b(tile[rcol+3][crow]);
    *(us4*)(out + (size_t)(c0 + crow) * R + (r0 + rcol)) = o;
  }
}

// ------- bf16 GEMM (R10: 128^2 tile, 512-thr wave split): C = A*BT^T + bias -------
// BK=64, 2 LDS buffers (64 KB -> 2 blk/CU => 16 waves/CU), glds16 staging w/
// pre-swizzled global source (rule #21), single __syncthreads per K-step.
// 8 waves 2x4: wave owns 64x32 output (4 mf x 2 nf), 16 MFMA/step.
// MODE0 v-blocks (bn>=32): epilogue transposes through LDS so the v^T write is
// coalesced 16B rows instead of a 64-lane 4KB-stride 2B scatter.
template<int MODE>
__global__ __launch_bounds__(512, 4) void gemm_kernel(
    const unsigned short* __restrict__ A,
    const unsigned short* __restrict__ BT,
    const float* __restrict__ bias,
    unsigned short* __restrict__ qb,
    unsigned short* __restrict__ kb,
    unsigned short* __restrict__ vtb,
    float* __restrict__ outp)
{
  constexpr int K = 2048;
  constexpr int NT = K / 64;
  __shared__ short lA[2][128 * 64];
  __shared__ short lB[2][128 * 64];
  const int tid = threadIdx.x, lane = tid & 63, wid = tid >> 6;
  const int l16 = lane & 15, lhi = lane >> 4;
  const int wm = wid >> 2, wn = wid & 3;
  const int bm = blockIdx.x, bn = blockIdx.y;

  const char* Abase = (const char*)(A + (size_t)bm * 128 * K);
  const char* Bbase = (const char*)(BT + (size_t)bn * 128 * K);

  // staging: chunk c = wid*2 + j (1 KB each, 16 chunks per operand)
  const char* agp[2]; const char* bgp[2];
  int dst[2];
#pragma unroll
  for (int j = 0; j < 2; j++){
    int c = wid * 2 + j;
    int row = c * 8 + (lane >> 3);
    int col = ((lane & 7) * 16) ^ ((lane >> 3) << 4);   // row&7 == lane>>3
    agp[j] = Abase + (size_t)row * (K * 2) + col;       // + kt*128
    bgp[j] = Bbase + (size_t)row * (K * 2) + col;
    dst[j] = c * 1024;                   // HW adds lane*16
  }

  auto stage = [&](int kt, int buf){
    char* bA = (char*)lA[buf]; char* bB = (char*)lB[buf];
#pragma unroll
    for (int j = 0; j < 2; j++){
      glds16(agp[j] + kt * 128, bA + dst[j]);
      glds16(bgp[j] + kt * 128, bB + dst[j]);
    }
  };

  f32x4 acc[4][2];
  f32x4 z = {0.f, 0.f, 0.f, 0.f};
#pragma unroll
  for (int i = 0; i < 4; i++)
#pragma unroll
    for (int j = 0; j < 2; j++) acc[i][j] = z;

  stage(0, 0);
  __syncthreads();
  int cur = 0;
  for (int kt = 0; kt < NT; ++kt){
    if (kt + 1 < NT) stage(kt + 1, cur ^ 1);   // prefetch into cur^1
#pragma unroll
    for (int kk = 0; kk < 2; kk++){
      bf16x8 af[4], bfr[2];
#pragma unroll
      for (int mf = 0; mf < 4; mf++){
        int row = wm * 64 + mf * 16 + l16;
        int byte = (row * 128 + kk * 64 + lhi * 16) ^ ((row & 7) << 4);
        af[mf] = *(const bf16x8*)((const char*)lA[cur] + byte);
      }
#pragma unroll
      for (int nf = 0; nf < 2; nf++){
        int row = wn * 32 + nf * 16 + l16;
        int byte = (row * 128 + kk * 64 + lhi * 16) ^ ((row & 7) << 4);
        bfr[nf] = *(const bf16x8*)((const char*)lB[cur] + byte);
      }
      __builtin_amdgcn_s_setprio(1);
#pragma unroll
      for (int mf = 0; mf < 4; mf++)
#pragma unroll
        for (int nf = 0; nf < 2; nf++)
          acc[mf][nf] = mfma16(af[mf], bfr[nf], acc[mf][nf]);
      __builtin_amdgcn_s_setprio(0);
    }
    __syncthreads();   // drains vmcnt (glds of cur^1 complete) + retires reads of cur
    cur ^= 1;
  }

  const int row0 = bm * 128 + wm * 64;
  const int col0 = bn * 128 + wn * 32;
  if (MODE == 0){
    if (bn < 32){
      // q / k blocks: direct coalesced element writes (which is 0 or 1)
#pragma unroll
      for (int nf = 0; nf < 2; nf++){
        int colb = col0 + nf * 16;
        float bv = bias[colb + l16];
        int which = colb >> 11;
        int h = (colb >> 7) & 15;
        int e = (colb & 127) + l16;
#pragma unroll
        for (int mf = 0; mf < 4; mf++){
#pragma unroll
          for (int r = 0; r < 4; r++){
            int row = row0 + mf * 16 + lhi * 4 + r;
            int b = row >> 11, t = row & 2047;
            float v = acc[mf][nf][r] + bv;
            size_t bh = (size_t)(b * 16 + h);
            if (which == 0) qb[(bh * 2048 + t) * 128 + e] = f2b(v * 0.08838834764831845f);
            else            kb[(bh * 2048 + t) * 128 + e] = f2b(v);
          }
        }
      }
    } else {
      // v blocks: transpose through LDS (reuse lA; K-loop's final barrier freed it).
      // LDS tile [e][t]: byte = e*256 + ((t*2) ^ ((e&7)<<4))  (rule #21: same XOR
      // on write and read; write conflicts 2-way = free).
      char* tb = (char*)lA;
      const int h = bn - 32, b = bm >> 4, t0 = (bm & 15) * 128;
#pragma unroll
      for (int nf = 0; nf < 2; nf++){
        int e = wn * 32 + nf * 16 + l16;
        float bv = bias[4096 + h * 128 + e];
#pragma unroll
        for (int mf = 0; mf < 4; mf++){
#pragma unroll
          for (int r = 0; r < 4; r++){
            int t = wm * 64 + mf * 16 + lhi * 4 + r;
            int byte = e * 256 + ((t * 2) ^ ((e & 7) << 4));
            *(unsigned short*)(tb + byte) = f2b(acc[mf][nf][r] + bv);
          }
        }
      }
      __syncthreads();
      // coalesced out: thread -> row ep, 32 t's (4 x 16B chunks)
      const int ep = tid >> 2, tq = (tid & 3) * 32;
      unsigned short* dstp = vtb + ((size_t)(b * 16 + h) * 128 + ep) * 2048 + t0 + tq;
      const char* srow = tb + ep * 256;
#pragma unroll
      for (int c = 0; c < 4; c++){
        int t = tq + c * 8;
        int4v v4 = *(const int4v*)(srow + ((t * 2) ^ ((ep & 7) << 4)));
        *(int4v*)(dstp + c * 8) = v4;
      }
    }
  } else {
#pragma unroll
    for (int nf = 0; nf < 2; nf++){
      int col = col0 + nf * 16 + l16;
      float bv = bias[col];
#pragma unroll
      for (int mf = 0; mf < 4; mf++){
#pragma unroll
        for (int r = 0; r < 4; r++){
          int row = row0 + mf * 16 + lhi * 4 + r;
          outp[(size_t)row * 2048 + col] = acc[mf][nf][r] + bv;
        }
      }
    }
  }
}

// ---------------- flash attention v2 (R10): 32x32 MFMA, swapped QK^T,
//                  in-reg softmax, K+V^T LDS dbuf, glds16 staging.
//                  PV cross-half exchange via v_permlane32_swap_b32 (T12 prim):
//                  swap(D=A,S=B): new_D = {A_lo,B_lo} = pw.x-pattern,
//                                 new_S = {A_hi,B_hi} = pw.z-pattern — replaces
//                  2 ds_bpermute + 8 cndmask per kk2 with 2 VALU ops. ----------
__global__ __launch_bounds__(256, 2) void attn_kernel(
    const unsigned short* __restrict__ q_buf,
    const unsigned short* __restrict__ k_buf,
    const unsigned short* __restrict__ vt_buf,
    unsigned short* __restrict__ attn_out)
{
  constexpr int L = 2048, NT = L / 64;
  __shared__ short lK[2][64 * 128];   // [key][e] rows 256 B, swizzled ^((key&7)<<4)
  __shared__ short lVT[2][128 * 64];  // [e][key] rows 128 B, swizzled ^((e&7)<<4)
  const int tid = threadIdx.x, lane = tid & 63, wid = tid >> 6;
  const int l31 = lane & 31, lhi2 = lane >> 5;

  const int d = blockIdx.y * 16 + blockIdx.x;
  const int bh = (d & 7) + 8 * ((d >> 3) & 3);
  const int qi = d >> 5;
  const int qbase = qi * 128;

  const unsigned short* qp = q_buf + (size_t)bh * L * 128;
  const char* kp2 = (const char*)(k_buf + (size_t)bh * L * 128);
  const char* vp2 = (const char*)(vt_buf + (size_t)bh * 128 * L);

  bf16x8 qf[8];
  {
    const unsigned short* qr = qp + (size_t)(qbase + wid * 32 + l31) * 128 + lhi2 * 8;
#pragma unroll
    for (int kk = 0; kk < 8; kk++)
      qf[kk] = *(const bf16x8*)(qr + kk * 16);
  }

  const char* kgp[4]; const char* vgp[4];
  int kdst[4], vdst[4];
#pragma unroll
  for (int i = 0; i < 4; i++){
    int c = wid * 4 + i;
    { int row = c * 4 + (lane >> 4);
      int col = ((lane & 15) * 16) ^ ((row & 7) << 4);
      kgp[i] = kp2 + row * 256 + col;
      kdst[i] = c * 1024; }
    { int e = c * 8 + (lane >> 3);
      int col = ((lane & 7) * 16) ^ ((e & 7) << 4);
      vgp[i] = vp2 + (size_t)e * 4096 + col;
      vdst[i] = c * 1024; }
  }

  auto stage = [&](int kt, int buf){
    char* bK = (char*)lK[buf]; char* bV = (char*)lVT[buf];
#pragma unroll
    for (int i = 0; i < 4; i++){
      glds16(kgp[i] + kt * 16384, bK + kdst[i]);
      glds16(vgp[i] + (size_t)kt * 128, bV + vdst[i]);
    }
  };

  f32x16 oacc[4];
#pragma unroll
  for (int nf = 0; nf < 4; nf++)
#pragma unroll
    for (int j = 0; j < 16; j++) oacc[nf][j] = 0.f;
  float m = -1e30f, ml2 = 0.f, lsum = 0.f;

  stage(0, 0);
  __syncthreads();
  int cur = 0;
  for (int kt = 0; kt < NT; ++kt){
    if (kt + 1 < NT) stage(kt + 1, cur ^ 1);
    const char* cK = (const char*)lK[cur];
    const char* cV = (const char*)lVT[cur];

    f32x16 sf[2];
#pragma unroll
    for (int mf = 0; mf < 2; mf++)
#pragma unroll
      for (int j = 0; j < 16; j++) sf[mf][j] = 0.f;
    __builtin_amdgcn_s_setprio(1);
#pragma unroll
    for (int kk = 0; kk < 8; kk++){
#pragma unroll
      for (int mf = 0; mf < 2; mf++){
        int byte = ((l31 * 256 + kk * 32 + lhi2 * 16) ^ ((l31 & 7) << 4)) + mf * 8192;
        bf16x8 kf = *(const bf16x8*)(cK + byte);
        sf[mf] = mfma32(kf, qf[kk], sf[mf]);
      }
    }
    __builtin_amdgcn_s_setprio(0);

    // row max: v_max3-friendly tree (T17)
    float pm[8];
#pragma unroll
    for (int g = 0; g < 8; g++){
      const float* s = (const float*)&sf[g >> 2] + (g & 3) * 4;
      pm[g] = fmaxf(max3f(s[0], s[1], s[2]), s[3]);
    }
    float tm = max3f(max3f(pm[0], pm[1], pm[2]),
                     max3f(pm[3], pm[4], pm[5]),
                     fmaxf(pm[6], pm[7]));
    tm = fmaxf(tm, __shfl_xor(tm, 32, 64));

    if (!__all(tm <= m + 8.0f)){
      float mn = fmaxf(m, tm);
      float alpha = __builtin_exp2f((m - mn) * LOG2E);
      m = mn; ml2 = mn * LOG2E;
      lsum *= alpha;
#pragma unroll
      for (int reg = 0; reg < 16; reg++){
        int row = (reg & 3) + 8 * (reg >> 2) + 4 * lhi2;
        float ar = __shfl(alpha, row | (lane & 32), 64);
#pragma unroll
        for (int nf = 0; nf < 4; nf++) oacc[nf][reg] *= ar;
      }
    }

    float pex[2][16];
    float rs = 0.f;
#pragma unroll
    for (int mf = 0; mf < 2; mf++)
#pragma unroll
      for (int j = 0; j < 16; j++){
        float p = __builtin_exp2f(__builtin_fmaf(sf[mf][j], LOG2E, -ml2));
        pex[mf][j] = p; rs += p;
      }
    rs += __shfl_xor(rs, 32, 64);
    lsum += rs;

    unsigned W[2][4][2];
#pragma unroll
    for (int mf = 0; mf < 2; mf++)
#pragma unroll
      for (int g = 0; g < 4; g++)
#pragma unroll
        for (int h = 0; h < 2; h++)
          W[mf][g][h] = (unsigned)f2bf(pex[mf][g * 4 + 2 * h]) |
                        ((unsigned)f2bf(pex[mf][g * 4 + 2 * h + 1]) << 16);

    __builtin_amdgcn_s_setprio(1);
#pragma unroll
    for (int kk2 = 0; kk2 < 4; kk2++){
      const int mfp = kk2 >> 1, gA = 2 * (kk2 & 1), gB = gA + 1;
      unsigned a0 = W[mfp][gA][0], a1 = W[mfp][gA][1];
      unsigned b0 = W[mfp][gB][0], b1 = W[mfp][gB][1];
      // After swap: a = {A_lo, B_lo} (old pw.x/pw.y), b = {A_hi, B_hi} (old pw.z/pw.w)
      asm volatile("v_permlane32_swap_b32 %0, %1" : "+v"(a0), "+v"(b0));
      asm volatile("v_permlane32_swap_b32 %0, %1" : "+v"(a1), "+v"(b1));
      int4v pw;
      pw.x = (int)a0; pw.y = (int)a1; pw.z = (int)b0; pw.w = (int)b1;
      bf16x8 pa = __builtin_bit_cast(bf16x8, pw);
#pragma unroll
      for (int nf = 0; nf < 4; nf++){
        int byte = ((l31 * 128 + kk2 * 32 + lhi2 * 16) ^ ((l31 & 7) << 4)) + nf * 4096;
        bf16x8 vb = *(const bf16x8*)(cV + byte);
        oacc[nf] = mfma32(pa, vb, oacc[nf]);
      }
    }
    __builtin_amdgcn_s_setprio(0);

    __syncthreads();
    cur ^= 1;
  }

  const int b = bh >> 4, h = bh & 15;
  float rl = 1.0f / lsum;
#pragma unroll
  for (int reg = 0; reg < 16; reg++){
    int row = (reg & 3) + 8 * (reg >> 2) + 4 * lhi2;
    float rr = __shfl(rl, row | (lane & 32), 64);
    size_t base = ((size_t)(b * L + qbase + wid * 32 + row)) * 2048 + h * 128 + l31;
#pragma unroll
    for (int nf = 0; nf < 4; nf++)
      attn_out[base + nf * 32] = f2b(oacc[nf][reg] * rr);
  }
}

extern "C" void kernel_launch(void* const* d_in, const int* in_sizes, int n_in,
                              void* d_out, int out_size, void* d_ws, size_t ws_size,
                              hipStream_t stream) {
  const float* x     = (const float*)d_in[0];
  const float* w_qkv = (const float*)d_in[1];
  const float* b_qkv = (const float*)d_in[2];
  const float* w_out = (const float*)d_in[3];
  const float* b_out = (const float*)d_in[4];
  float* out = (float*)d_out;

  unsigned short* ws = (unsigned short*)d_ws;
  unsigned short* xb    = ws;                               // 4096*2048
  unsigned short* wqkvT = xb    + (size_t)4096 * 2048;      // 6144*2048
  unsigned short* woutT = wqkvT + (size_t)6144 * 2048;      // 2048*2048
  unsigned short* qb    = woutT + (size_t)2048 * 2048;      // [2,16,2048,128]
  unsigned short* kb    = qb    + (size_t)2 * 16 * 2048 * 128;
  unsigned short* vtb   = kb    + (size_t)2 * 16 * 2048 * 128;  // [2,16,128,2048]
  unsigned short* attnb = vtb   + (size_t)2 * 16 * 2048 * 128;  // 4096*2048

  cast_bf16_kernel<<<2048, 256, 0, stream>>>((const float4*)x, (us4*)xb, (4096 * 2048) / 4);
  transpose2_kernel<<<dim3(128, 32), 256, 0, stream>>>(w_qkv, wqkvT, w_out, woutT);
  gemm_kernel<0><<<dim3(32, 48), 512, 0, stream>>>(xb, wqkvT, b_qkv, qb, kb, vtb, nullptr);
  attn_kernel<<<dim3(16, 32), 256, 0, stream>>>(qb, kb, vtb, attnb);
  gemm_kernel<1><<<dim3(32, 16), 512, 0, stream>>>(attnb, woutT, b_out, nullptr, nullptr, nullptr, out);
}

// Round 18
// 267.972 us; speedup vs baseline: 1.3891x; 1.0028x over previous
//
#include <hip/hip_runtime.h>

typedef __attribute__((ext_vector_type(8))) short bf16x8;
typedef __attribute__((ext_vector_type(4))) float f32x4;
typedef __attribute__((ext_vector_type(16))) float f32x16;
typedef __attribute__((ext_vector_type(4))) int int4v;
typedef __attribute__((ext_vector_type(4))) unsigned short us4;

#define LOG2E 1.4426950408889634f

__device__ __forceinline__ unsigned short f2b(float f){
  unsigned u = __builtin_bit_cast(unsigned, f);
  u = (u + 0x7fffu + ((u >> 16) & 1u)) >> 16;
  return (unsigned short)u;
}
// round-to-nearest (ties up) — 0.5 ulp, 2 VALU ops
__device__ __forceinline__ unsigned short f2bf(float f){
  unsigned u = __builtin_bit_cast(unsigned, f);
  return (unsigned short)((u + 0x8000u) >> 16);
}

__device__ __forceinline__ f32x4 mfma16(bf16x8 a, bf16x8 b, f32x4 c){
  return __builtin_amdgcn_mfma_f32_16x16x32_bf16(a, b, c, 0, 0, 0);
}
__device__ __forceinline__ f32x16 mfma32(bf16x8 a, bf16x8 b, f32x16 c){
  return __builtin_amdgcn_mfma_f32_32x32x16_bf16(a, b, c, 0, 0, 0);
}
// 3-input max — clang fuses nested fmaxf to v_max3_f32 (T17)
__device__ __forceinline__ float max3f(float a, float b, float c){
  return fmaxf(fmaxf(a, b), c);
}

typedef const __attribute__((address_space(1))) void* gas_t;
typedef __attribute__((address_space(3))) void* las_t;
__device__ __forceinline__ void glds16(const void* g, void* l){
  __builtin_amdgcn_global_load_lds((gas_t)g, (las_t)l, 16, 0, 0);
}

// ---------------- cast fp32 -> bf16 (vectorized) ----------------
__global__ __launch_bounds__(256) void cast_bf16_kernel(const float4* __restrict__ in,
                                                        us4* __restrict__ out, int n4){
  int i = blockIdx.x * 256 + threadIdx.x;
  int stride = gridDim.x * 256;
  for (; i < n4; i += stride){
    float4 v = in[i];
    us4 o; o.x = f2b(v.x); o.y = f2b(v.y); o.z = f2b(v.z); o.w = f2b(v.w);
    out[i] = o;
  }
}

// ------ merged transpose+cast for both weights: in[R][C] fp32 -> out[C][R] bf16 ----
__global__ __launch_bounds__(256) void transpose2_kernel(const float* __restrict__ in0,
                                                         unsigned short* __restrict__ out0,
                                                         const float* __restrict__ in1,
                                                         unsigned short* __restrict__ out1){
  __shared__ float tile[64][65];
  const int tid = threadIdx.x;
  const bool first = blockIdx.x < 96;
  const float* in = first ? in0 : in1;
  unsigned short* out = first ? out0 : out1;
  const int C = first ? 6144 : 2048;
  const int R = 2048;
  const int bx = first ? blockIdx.x : blockIdx.x - 96;
  const int c0 = bx * 64, r0 = blockIdx.y * 64;
#pragma unroll
  for (int p = 0; p < 4; p++){
    int idx = p * 1024 + tid * 4;
    int rr = idx >> 6, cc = idx & 63;
    float4 v = *(const float4*)(in + (size_t)(r0 + rr) * C + (c0 + cc));
    tile[rr][cc+0] = v.x; tile[rr][cc+1] = v.y; tile[rr][cc+2] = v.z; tile[rr][cc+3] = v.w;
  }
  __syncthreads();
#pragma unroll
  for (int p = 0; p < 4; p++){
    int idx = p * 1024 + tid * 4;
    int crow = idx >> 6, rcol = idx & 63;
    us4 o;
    o.x = f2b(tile[rcol+0][crow]); o.y = f2b(tile[rcol+1][crow]);
    o.z = f2b(tile[rcol+2][crow]); o.w = f2b(tile[rcol+3][crow]);
    *(us4*)(out + (size_t)(c0 + crow) * R + (r0 + rcol)) = o;
  }
}

// ------- bf16 GEMM (R10: 128^2 tile, 512-thr wave split): C = A*BT^T + bias -------
// BK=64, 2 LDS buffers (64 KB -> 2 blk/CU => 16 waves/CU), glds16 staging w/
// pre-swizzled global source (rule #21), single __syncthreads per K-step.
// 8 waves 2x4: wave owns 64x32 output (4 mf x 2 nf), 16 MFMA/step.
// MODE0 v-blocks (bn>=32): epilogue transposes through LDS so the v^T write is
// coalesced 16B rows instead of a 64-lane 4KB-stride 2B scatter.
template<int MODE>
__global__ __launch_bounds__(512, 4) void gemm_kernel(
    const unsigned short* __restrict__ A,
    const unsigned short* __restrict__ BT,
    const float* __restrict__ bias,
    unsigned short* __restrict__ qb,
    unsigned short* __restrict__ kb,
    unsigned short* __restrict__ vtb,
    float* __restrict__ outp)
{
  constexpr int K = 2048;
  constexpr int NT = K / 64;
  __shared__ short lA[2][128 * 64];
  __shared__ short lB[2][128 * 64];
  const int tid = threadIdx.x, lane = tid & 63, wid = tid >> 6;
  const int l16 = lane & 15, lhi = lane >> 4;
  const int wm = wid >> 2, wn = wid & 3;
  const int bm = blockIdx.x, bn = blockIdx.y;

  const char* Abase = (const char*)(A + (size_t)bm * 128 * K);
  const char* Bbase = (const char*)(BT + (size_t)bn * 128 * K);

  // staging: chunk c = wid*2 + j (1 KB each, 16 chunks per operand)
  const char* agp[2]; const char* bgp[2];
  int dst[2];
#pragma unroll
  for (int j = 0; j < 2; j++){
    int c = wid * 2 + j;
    int row = c * 8 + (lane >> 3);
    int col = ((lane & 7) * 16) ^ ((lane >> 3) << 4);   // row&7 == lane>>3
    agp[j] = Abase + (size_t)row * (K * 2) + col;       // + kt*128
    bgp[j] = Bbase + (size_t)row * (K * 2) + col;
    dst[j] = c * 1024;                   // HW adds lane*16
  }

  auto stage = [&](int kt, int buf){
    char* bA = (char*)lA[buf]; char* bB = (char*)lB[buf];
#pragma unroll
    for (int j = 0; j < 2; j++){
      glds16(agp[j] + kt * 128, bA + dst[j]);
      glds16(bgp[j] + kt * 128, bB + dst[j]);
    }
  };

  f32x4 acc[4][2];
  f32x4 z = {0.f, 0.f, 0.f, 0.f};
#pragma unroll
  for (int i = 0; i < 4; i++)
#pragma unroll
    for (int j = 0; j < 2; j++) acc[i][j] = z;

  stage(0, 0);
  __syncthreads();
  int cur = 0;
  for (int kt = 0; kt < NT; ++kt){
    if (kt + 1 < NT) stage(kt + 1, cur ^ 1);   // prefetch into cur^1
#pragma unroll
    for (int kk = 0; kk < 2; kk++){
      bf16x8 af[4], bfr[2];
#pragma unroll
      for (int mf = 0; mf < 4; mf++){
        int row = wm * 64 + mf * 16 + l16;
        int byte = (row * 128 + kk * 64 + lhi * 16) ^ ((row & 7) << 4);
        af[mf] = *(const bf16x8*)((const char*)lA[cur] + byte);
      }
#pragma unroll
      for (int nf = 0; nf < 2; nf++){
        int row = wn * 32 + nf * 16 + l16;
        int byte = (row * 128 + kk * 64 + lhi * 16) ^ ((row & 7) << 4);
        bfr[nf] = *(const bf16x8*)((const char*)lB[cur] + byte);
      }
      __builtin_amdgcn_s_setprio(1);
#pragma unroll
      for (int mf = 0; mf < 4; mf++)
#pragma unroll
        for (int nf = 0; nf < 2; nf++)
          acc[mf][nf] = mfma16(af[mf], bfr[nf], acc[mf][nf]);
      __builtin_amdgcn_s_setprio(0);
    }
    __syncthreads();   // drains vmcnt (glds of cur^1 complete) + retires reads of cur
    cur ^= 1;
  }

  const int row0 = bm * 128 + wm * 64;
  const int col0 = bn * 128 + wn * 32;
  if (MODE == 0){
    if (bn < 32){
      // q / k blocks: direct coalesced element writes (which is 0 or 1)
#pragma unroll
      for (int nf = 0; nf < 2; nf++){
        int colb = col0 + nf * 16;
        float bv = bias[colb + l16];
        int which = colb >> 11;
        int h = (colb >> 7) & 15;
        int e = (colb & 127) + l16;
#pragma unroll
        for (int mf = 0; mf < 4; mf++){
#pragma unroll
          for (int r = 0; r < 4; r++){
            int row = row0 + mf * 16 + lhi * 4 + r;
            int b = row >> 11, t = row & 2047;
            float v = acc[mf][nf][r] + bv;
            size_t bh = (size_t)(b * 16 + h);
            if (which == 0) qb[(bh * 2048 + t) * 128 + e] = f2b(v * 0.08838834764831845f);
            else            kb[(bh * 2048 + t) * 128 + e] = f2b(v);
          }
        }
      }
    } else {
      // v blocks: transpose through LDS (reuse lA; K-loop's final barrier freed it).
      // LDS tile [e][t]: byte = e*256 + ((t*2) ^ ((e&7)<<4))  (rule #21: same XOR
      // on write and read; write conflicts 2-way = free).
      char* tb = (char*)lA;
      const int h = bn - 32, b = bm >> 4, t0 = (bm & 15) * 128;
#pragma unroll
      for (int nf = 0; nf < 2; nf++){
        int e = wn * 32 + nf * 16 + l16;
        float bv = bias[4096 + h * 128 + e];
#pragma unroll
        for (int mf = 0; mf < 4; mf++){
#pragma unroll
          for (int r = 0; r < 4; r++){
            int t = wm * 64 + mf * 16 + lhi * 4 + r;
            int byte = e * 256 + ((t * 2) ^ ((e & 7) << 4));
            *(unsigned short*)(tb + byte) = f2b(acc[mf][nf][r] + bv);
          }
        }
      }
      __syncthreads();
      // coalesced out: thread -> row ep, 32 t's (4 x 16B chunks)
      const int ep = tid >> 2, tq = (tid & 3) * 32;
      unsigned short* dstp = vtb + ((size_t)(b * 16 + h) * 128 + ep) * 2048 + t0 + tq;
      const char* srow = tb + ep * 256;
#pragma unroll
      for (int c = 0; c < 4; c++){
        int t = tq + c * 8;
        int4v v4 = *(const int4v*)(srow + ((t * 2) ^ ((ep & 7) << 4)));
        *(int4v*)(dstp + c * 8) = v4;
      }
    }
  } else {
#pragma unroll
    for (int nf = 0; nf < 2; nf++){
      int col = col0 + nf * 16 + l16;
      float bv = bias[col];
#pragma unroll
      for (int mf = 0; mf < 4; mf++){
#pragma unroll
        for (int r = 0; r < 4; r++){
          int row = row0 + mf * 16 + lhi * 4 + r;
          outp[(size_t)row * 2048 + col] = acc[mf][nf][r] + bv;
        }
      }
    }
  }
}

// ---------------- flash attention v2 (R16): 32x32 MFMA, swapped QK^T,
//                  in-reg softmax, K+V^T LDS dbuf, glds16 staging.
//                  PV cross-half exchange via v_permlane32_swap_b32 (T12 prim;
//                  operands hold DIFFERENT values so regs stay distinct —
//                  never pass two copies of one value to the swap). ----------
__global__ __launch_bounds__(256, 2) void attn_kernel(
    const unsigned short* __restrict__ q_buf,
    const unsigned short* __restrict__ k_buf,
    const unsigned short* __restrict__ vt_buf,
    unsigned short* __restrict__ attn_out)
{
  constexpr int L = 2048, NT = L / 64;
  __shared__ short lK[2][64 * 128];   // [key][e] rows 256 B, swizzled ^((key&7)<<4)
  __shared__ short lVT[2][128 * 64];  // [e][key] rows 128 B, swizzled ^((e&7)<<4)
  const int tid = threadIdx.x, lane = tid & 63, wid = tid >> 6;
  const int l31 = lane & 31, lhi2 = lane >> 5;

  const int d = blockIdx.y * 16 + blockIdx.x;
  const int bh = (d & 7) + 8 * ((d >> 3) & 3);
  const int qi = d >> 5;
  const int qbase = qi * 128;

  const unsigned short* qp = q_buf + (size_t)bh * L * 128;
  const char* kp2 = (const char*)(k_buf + (size_t)bh * L * 128);
  const char* vp2 = (const char*)(vt_buf + (size_t)bh * 128 * L);

  bf16x8 qf[8];
  {
    const unsigned short* qr = qp + (size_t)(qbase + wid * 32 + l31) * 128 + lhi2 * 8;
#pragma unroll
    for (int kk = 0; kk < 8; kk++)
      qf[kk] = *(const bf16x8*)(qr + kk * 16);
  }

  const char* kgp[4]; const char* vgp[4];
  int kdst[4], vdst[4];
#pragma unroll
  for (int i = 0; i < 4; i++){
    int c = wid * 4 + i;
    { int row = c * 4 + (lane >> 4);
      int col = ((lane & 15) * 16) ^ ((row & 7) << 4);
      kgp[i] = kp2 + row * 256 + col;
      kdst[i] = c * 1024; }
    { int e = c * 8 + (lane >> 3);
      int col = ((lane & 7) * 16) ^ ((e & 7) << 4);
      vgp[i] = vp2 + (size_t)e * 4096 + col;
      vdst[i] = c * 1024; }
  }

  auto stage = [&](int kt, int buf){
    char* bK = (char*)lK[buf]; char* bV = (char*)lVT[buf];
#pragma unroll
    for (int i = 0; i < 4; i++){
      glds16(kgp[i] + kt * 16384, bK + kdst[i]);
      glds16(vgp[i] + (size_t)kt * 128, bV + vdst[i]);
    }
  };

  f32x16 oacc[4];
#pragma unroll
  for (int nf = 0; nf < 4; nf++)
#pragma unroll
    for (int j = 0; j < 16; j++) oacc[nf][j] = 0.f;
  float m = -1e30f, ml2 = 0.f, lsum = 0.f;

  stage(0, 0);
  __syncthreads();
  int cur = 0;
  for (int kt = 0; kt < NT; ++kt){
    if (kt + 1 < NT) stage(kt + 1, cur ^ 1);
    const char* cK = (const char*)lK[cur];
    const char* cV = (const char*)lVT[cur];

    f32x16 sf[2];
#pragma unroll
    for (int mf = 0; mf < 2; mf++)
#pragma unroll
      for (int j = 0; j < 16; j++) sf[mf][j] = 0.f;
    __builtin_amdgcn_s_setprio(1);
#pragma unroll
    for (int kk = 0; kk < 8; kk++){
#pragma unroll
      for (int mf = 0; mf < 2; mf++){
        int byte = ((l31 * 256 + kk * 32 + lhi2 * 16) ^ ((l31 & 7) << 4)) + mf * 8192;
        bf16x8 kf = *(const bf16x8*)(cK + byte);
        sf[mf] = mfma32(kf, qf[kk], sf[mf]);
      }
    }
    __builtin_amdgcn_s_setprio(0);

    // row max: v_max3-friendly tree (T17)
    float pm[8];
#pragma unroll
    for (int g = 0; g < 8; g++){
      const float* s = (const float*)&sf[g >> 2] + (g & 3) * 4;
      pm[g] = fmaxf(max3f(s[0], s[1], s[2]), s[3]);
    }
    float tm = max3f(max3f(pm[0], pm[1], pm[2]),
                     max3f(pm[3], pm[4], pm[5]),
                     fmaxf(pm[6], pm[7]));
    tm = fmaxf(tm, __shfl_xor(tm, 32, 64));

    if (!__all(tm <= m + 8.0f)){
      float mn = fmaxf(m, tm);
      float alpha = __builtin_exp2f((m - mn) * LOG2E);
      m = mn; ml2 = mn * LOG2E;
      lsum *= alpha;
#pragma unroll
      for (int reg = 0; reg < 16; reg++){
        int row = (reg & 3) + 8 * (reg >> 2) + 4 * lhi2;
        float ar = __shfl(alpha, row | (lane & 32), 64);
#pragma unroll
        for (int nf = 0; nf < 4; nf++) oacc[nf][reg] *= ar;
      }
    }

    float pex[2][16];
    float rs = 0.f;
#pragma unroll
    for (int mf = 0; mf < 2; mf++)
#pragma unroll
      for (int j = 0; j < 16; j++){
        float p = __builtin_exp2f(__builtin_fmaf(sf[mf][j], LOG2E, -ml2));
        pex[mf][j] = p; rs += p;
      }
    rs += __shfl_xor(rs, 32, 64);
    lsum += rs;

    unsigned W[2][4][2];
#pragma unroll
    for (int mf = 0; mf < 2; mf++)
#pragma unroll
      for (int g = 0; g < 4; g++)
#pragma unroll
        for (int h = 0; h < 2; h++)
          W[mf][g][h] = (unsigned)f2bf(pex[mf][g * 4 + 2 * h]) |
                        ((unsigned)f2bf(pex[mf][g * 4 + 2 * h + 1]) << 16);

    __builtin_amdgcn_s_setprio(1);
#pragma unroll
    for (int kk2 = 0; kk2 < 4; kk2++){
      const int mfp = kk2 >> 1, gA = 2 * (kk2 & 1), gB = gA + 1;
      unsigned a0 = W[mfp][gA][0], a1 = W[mfp][gA][1];
      unsigned b0 = W[mfp][gB][0], b1 = W[mfp][gB][1];
      // After swap: a = {A_lo, B_lo}, b = {A_hi, B_hi}
      asm volatile("v_permlane32_swap_b32 %0, %1" : "+v"(a0), "+v"(b0));
      asm volatile("v_permlane32_swap_b32 %0, %1" : "+v"(a1), "+v"(b1));
      int4v pw;
      pw.x = (int)a0; pw.y = (int)a1; pw.z = (int)b0; pw.w = (int)b1;
      bf16x8 pa = __builtin_bit_cast(bf16x8, pw);
#pragma unroll
      for (int nf = 0; nf < 4; nf++){
        int byte = ((l31 * 128 + kk2 * 32 + lhi2 * 16) ^ ((l31 & 7) << 4)) + nf * 4096;
        bf16x8 vb = *(const bf16x8*)(cV + byte);
        oacc[nf] = mfma32(pa, vb, oacc[nf]);
      }
    }
    __builtin_amdgcn_s_setprio(0);

    __syncthreads();
    cur ^= 1;
  }

  const int b = bh >> 4, h = bh & 15;
  float rl = 1.0f / lsum;
#pragma unroll
  for (int reg = 0; reg < 16; reg++){
    int row = (reg & 3) + 8 * (reg >> 2) + 4 * lhi2;
    float rr = __shfl(rl, row | (lane & 32), 64);
    size_t base = ((size_t)(b * L + qbase + wid * 32 + row)) * 2048 + h * 128 + l31;
#pragma unroll
    for (int nf = 0; nf < 4; nf++)
      attn_out[base + nf * 32] = f2b(oacc[nf][reg] * rr);
  }
}

extern "C" void kernel_launch(void* const* d_in, const int* in_sizes, int n_in,
                              void* d_out, int out_size, void* d_ws, size_t ws_size,
                              hipStream_t stream) {
  const float* x     = (const float*)d_in[0];
  const float* w_qkv = (const float*)d_in[1];
  const float* b_qkv = (const float*)d_in[2];
  const float* w_out = (const float*)d_in[3];
  const float* b_out = (const float*)d_in[4];
  float* out = (float*)d_out;

  unsigned short* ws = (unsigned short*)d_ws;
  unsigned short* xb    = ws;                               // 4096*2048
  unsigned short* wqkvT = xb    + (size_t)4096 * 2048;      // 6144*2048
  unsigned short* woutT = wqkvT + (size_t)6144 * 2048;      // 2048*2048
  unsigned short* qb    = woutT + (size_t)2048 * 2048;      // [2,16,2048,128]
  unsigned short* kb    = qb    + (size_t)2 * 16 * 2048 * 128;
  unsigned short* vtb   = kb    + (size_t)2 * 16 * 2048 * 128;  // [2,16,128,2048]
  unsigned short* attnb = vtb   + (size_t)2 * 16 * 2048 * 128;  // 4096*2048

  cast_bf16_kernel<<<2048, 256, 0, stream>>>((const float4*)x, (us4*)xb, (4096 * 2048) / 4);
  transpose2_kernel<<<dim3(128, 32), 256, 0, stream>>>(w_qkv, wqkvT, w_out, woutT);
  gemm_kernel<0><<<dim3(32, 48), 512, 0, stream>>>(xb, wqkvT, b_qkv, qb, kb, vtb, nullptr);
  attn_kernel<<<dim3(16, 32), 256, 0, stream>>>(qb, kb, vtb, attnb);
  gemm_kernel<1><<<dim3(32, 16), 512, 0, stream>>>(attnb, woutT, b_out, nullptr, nullptr, nullptr, out);
}